// Round 4
// baseline (1235.103 us; speedup 1.0000x reference)
//
#include <hip/hip_runtime.h>
#include <cstdint>
#include <cstddef>

#define DEVINL __device__ __forceinline__

typedef short s16x8 __attribute__((ext_vector_type(8)));   // 8 bf16 in 4 VGPRs
typedef float f32x4 __attribute__((ext_vector_type(4)));

DEVINL unsigned short f2bf(float f) {
  unsigned u = __float_as_uint(f);
  unsigned r = (u + 0x7FFFu + ((u >> 16) & 1u)) >> 16;
  return (unsigned short)r;
}
DEVINL float bf2f(unsigned short b) { return __uint_as_float(((unsigned)b) << 16); }

__global__ __launch_bounds__(256) void fill_i32(int* __restrict__ p, int val, int n) {
  int i = blockIdx.x * 256 + threadIdx.x;
  if (i < n) p[i] = val;
}

// ---------------- bf16 hi/lo split conversions ----------------

__global__ __launch_bounds__(256) void cvt_split(const float* __restrict__ in,
                                                 unsigned short* __restrict__ hi,
                                                 unsigned short* __restrict__ lo, int n) {
  int i = blockIdx.x * 256 + threadIdx.x;
  if (i >= n) return;
  float f = in[i];
  unsigned short h = f2bf(f);
  float r = f - bf2f(h);
  hi[i] = h;
  lo[i] = f2bf(r);
}

// W[K,M] fp32 -> Wt_hi/lo[M,K] bf16 (transposed for contiguous B fragments)
__global__ __launch_bounds__(256) void cvt_w(const float* __restrict__ W,
                                             unsigned short* __restrict__ Wh,
                                             unsigned short* __restrict__ Wl,
                                             int K, int M) {
  int i = blockIdx.x * 256 + threadIdx.x;
  if (i >= K * M) return;
  int k = i / M, m = i - k * M;
  float f = W[i];
  unsigned short h = f2bf(f);
  float r = f - bf2f(h);
  Wh[(size_t)m * K + k] = h;
  Wl[(size_t)m * K + k] = f2bf(r);
}

// ---------------- A-resident fused 4-matrix MFMA GEMM (bf16x3) -------
// One wave owns 16 rows; A frags for the whole K live in registers.
// Sweeps z=0..3 weight matrices x col-groups, streaming W from L2.
struct GemmArgs {
  const unsigned short* Wh[4];
  const unsigned short* Wl[4];
  const float* bias[4];
  float* out[4];
};

template <int KC, int MT>   // KC = K/32, MT = M/64
__global__ __launch_bounds__(256) void gemm4_reg(
    const unsigned short* __restrict__ Ah, const unsigned short* __restrict__ Al,
    GemmArgs args, int N, int K, int M) {
  int wave = threadIdx.x >> 6;
  int lane = threadIdx.x & 63;
  int lrow = lane & 15;
  int quad = lane >> 4;
  int row = blockIdx.x * 64 + wave * 16 + lrow;
  int arow = row < N ? row : N - 1;          // clamp: stays in-bounds, garbage OK
  size_t abase = (size_t)arow * K + quad * 8;
  s16x8 a_h[KC], a_l[KC];
#pragma unroll
  for (int kc = 0; kc < KC; kc++) {
    a_h[kc] = *(const s16x8*)(Ah + abase + kc * 32);
    a_l[kc] = *(const s16x8*)(Al + abase + kc * 32);
  }
  int rbase = blockIdx.x * 64 + wave * 16 + quad * 4;
#pragma unroll
  for (int z = 0; z < 4; z++) {
    const unsigned short* __restrict__ Wh = args.Wh[z];
    const unsigned short* __restrict__ Wl = args.Wl[z];
    const float* __restrict__ bias = args.bias[z];
    float* __restrict__ C = args.out[z];
#pragma unroll 2
    for (int cg = 0; cg < MT * 4; cg++) {    // 16-col groups
      int col = cg * 16 + lrow;
      size_t wbase = (size_t)col * K + quad * 8;
      f32x4 acc = {};
#pragma unroll
      for (int kc = 0; kc < KC; kc++) {
        s16x8 w_h = *(const s16x8*)(Wh + wbase + kc * 32);
        s16x8 w_l = *(const s16x8*)(Wl + wbase + kc * 32);
        acc = __builtin_amdgcn_mfma_f32_16x16x32_bf16(a_h[kc], w_h, acc, 0, 0, 0);
        acc = __builtin_amdgcn_mfma_f32_16x16x32_bf16(a_l[kc], w_h, acc, 0, 0, 0);
        acc = __builtin_amdgcn_mfma_f32_16x16x32_bf16(a_h[kc], w_l, acc, 0, 0, 0);
      }
      float bv = bias[col];
#pragma unroll
      for (int r = 0; r < 4; r++) {
        int rr = rbase + r;
        if (rr < N) C[(size_t)rr * M + col] = acc[r] + bv;
      }
    }
  }
}

// ---------------- counting sort of edges by dst ----------------

__global__ __launch_bounds__(256) void hist_dst(const int* __restrict__ dst,
                                                int* __restrict__ cnt, int E) {
  int e = blockIdx.x * 256 + threadIdx.x;
  if (e < E) atomicAdd(&cnt[dst[e] + 1], 1);
}

__global__ __launch_bounds__(1024) void scan_hist(const int* __restrict__ cnt,
                                                  int* __restrict__ start,
                                                  int* __restrict__ off, int N) {
  __shared__ int sums[1024];
  const int CH = 20;
  int t = threadIdx.x;
  int base = t * CH;
  int local[CH];
  int tot = 0;
  if (base < N) {
#pragma unroll
    for (int i = 0; i < CH; i++) { local[i] = cnt[base + i]; tot += local[i]; }
  }
  sums[t] = tot;
  __syncthreads();
  for (int d = 1; d < 1024; d <<= 1) {
    int v = (t >= d) ? sums[t - d] : 0;
    __syncthreads();
    sums[t] += v;
    __syncthreads();
  }
  if (base < N) {
    int run = (t == 0) ? 0 : sums[t - 1];
#pragma unroll
    for (int i = 0; i < CH; i++) { start[base + i] = run; off[base + i] = run; run += local[i]; }
    if (base + CH == N) start[N] = run;
  }
}

__global__ __launch_bounds__(256) void scatter_edges(
    const int* __restrict__ src, const int* __restrict__ dst,
    const float* __restrict__ ea, int* __restrict__ off,
    int* __restrict__ src_s, float* __restrict__ ea_s, int* __restrict__ eid_s, int E) {
  int e = blockIdx.x * 256 + threadIdx.x;
  if (e >= E) return;
  int d = dst[e] + 1;
  int pos = atomicAdd(&off[d], 1);
  src_s[pos] = src[e] + 1;
  ea_s[pos] = ea[e];
  eid_s[pos] = e;
}

// ---------------- fused per-dst attention (flash-style) ----------------
template <int H, int LPH>
__global__ __launch_bounds__(256) void attn_fused(
    const float* __restrict__ q, const float* __restrict__ k,
    const float* __restrict__ v, const float* __restrict__ We,
    const int* __restrict__ start, const int* __restrict__ src_s,
    const float* __restrict__ ea_s, const int* __restrict__ eid_s,
    float* __restrict__ sc, float* __restrict__ outp,
    float* __restrict__ alpha, int Nn, float scale) {
  const int HC = H * LPH * 4;
  int w = (blockIdx.x * 256 + threadIdx.x) >> 6;
  int lane = threadIdx.x & 63;
  if (w >= Nn) return;
  int b = start[w], e = start[w + 1];
  if (b == e) return;
  bool act = lane < H * LPH;
  int idx = lane * 4;
  int head = lane / LPH;
  float4 q4 = make_float4(0.f, 0.f, 0.f, 0.f), We4 = q4;
  if (act) {
    q4 = *(const float4*)(q + (size_t)w * HC + idx);
    We4 = *(const float4*)(We + idx);
  }
  float m = -INFINITY, l = 0.f;
  float4 acc = make_float4(0.f, 0.f, 0.f, 0.f);
  for (int pos = b; pos < e; pos++) {
    int s = src_s[pos];
    float eav = ea_s[pos];
    float4 k4 = make_float4(0.f, 0.f, 0.f, 0.f);
    float4 v4 = k4;
    if (act) {
      k4 = *(const float4*)(k + (size_t)s * HC + idx);
      v4 = *(const float4*)(v + (size_t)s * HC + idx);
    }
    k4.x = fmaf(eav, We4.x, k4.x); k4.y = fmaf(eav, We4.y, k4.y);
    k4.z = fmaf(eav, We4.z, k4.z); k4.w = fmaf(eav, We4.w, k4.w);
    v4.x = fmaf(eav, We4.x, v4.x); v4.y = fmaf(eav, We4.y, v4.y);
    v4.z = fmaf(eav, We4.z, v4.z); v4.w = fmaf(eav, We4.w, v4.w);
    float p = q4.x * k4.x + q4.y * k4.y + q4.z * k4.z + q4.w * k4.w;
#pragma unroll
    for (int mm = 1; mm < LPH; mm <<= 1) p += __shfl_xor(p, mm, 64);
    float score = p * scale;
    if (act && (lane % LPH) == 0) sc[(size_t)pos * H + head] = score;
    float mn = fmaxf(m, score);
    float f = __expf(m - mn);
    float es = __expf(score - mn);
    l = l * f + es;
    m = mn;
    acc.x = fmaf(acc.x, f, es * v4.x);
    acc.y = fmaf(acc.y, f, es * v4.y);
    acc.z = fmaf(acc.z, f, es * v4.z);
    acc.w = fmaf(acc.w, f, es * v4.w);
  }
  float invl = 1.0f / (l + 1e-16f);
  if (act) {
    float* orow = outp + (size_t)w * HC + idx;
    float4 o = *(float4*)orow;
    o.x += acc.x * invl; o.y += acc.y * invl;
    o.z += acc.z * invl; o.w += acc.w * invl;
    *(float4*)orow = o;
  }
  for (int pos = b; pos < e; pos++) {
    if (act && (lane % LPH) == 0) {
      float sv = sc[(size_t)pos * H + head];
      alpha[(size_t)eid_s[pos] * H + head] = __expf(sv - m) * invl;
    }
  }
}

// ---------------- misc dense kernels ----------------

__global__ __launch_bounds__(256) void ln_relu(
    const float* __restrict__ in, const float* __restrict__ g,
    const float* __restrict__ b, float* __restrict__ o, int N) {
  int w = (blockIdx.x * 256 + threadIdx.x) >> 6;
  int lane = threadIdx.x & 63;
  if (w >= N) return;
  float4 x = *(const float4*)(in + (size_t)w * 256 + lane * 4);
  float s = x.x + x.y + x.z + x.w;
  float s2 = x.x * x.x + x.y * x.y + x.z * x.z + x.w * x.w;
  for (int m = 1; m < 64; m <<= 1) { s += __shfl_xor(s, m, 64); s2 += __shfl_xor(s2, m, 64); }
  float mu = s * (1.0f / 256.0f);
  float var = s2 * (1.0f / 256.0f) - mu * mu;
  float inv = rsqrtf(var + 1e-5f);
  float4 gv = *(const float4*)(g + lane * 4);
  float4 bv = *(const float4*)(b + lane * 4);
  float4 y;
  y.x = fmaxf(fmaf((x.x - mu) * inv, gv.x, bv.x), 0.f);
  y.y = fmaxf(fmaf((x.y - mu) * inv, gv.y, bv.y), 0.f);
  y.z = fmaxf(fmaf((x.z - mu) * inv, gv.z, bv.z), 0.f);
  y.w = fmaxf(fmaf((x.w - mu) * inv, gv.w, bv.w), 0.f);
  *(float4*)(o + (size_t)w * 256 + lane * 4) = y;
}

__global__ __launch_bounds__(192) void resid_pool2(
    const float* __restrict__ x, const float* __restrict__ x3,
    const int* __restrict__ batch, float* __restrict__ pooled,
    float* __restrict__ cnt, int N, int R) {
  int col = threadIdx.x;  // 0..191
  int r0 = blockIdx.x * R;
  int r1 = min(r0 + R, N);
  if (r0 >= N) return;
  float acc = 0.f;
  int cur = batch[r0];
  int run = 0;
  for (int r = r0; r < r1; r++) {
    int b = batch[r];
    if (b != cur) {
      atomicAdd(&pooled[cur * 192 + col], acc);
      if (col == 0) atomicAdd(&cnt[cur], (float)run);
      acc = 0.f; run = 0; cur = b;
    }
    size_t i = (size_t)r * 192 + col;
    acc += x[i] + fmaxf(x3[i], 0.f);
    run++;
  }
  atomicAdd(&pooled[cur * 192 + col], acc);
  if (col == 0) atomicAdd(&cnt[cur], (float)run);
}

__global__ __launch_bounds__(64) void head_mlp(
    const float* __restrict__ pooled, const float* __restrict__ cnt,
    const float* __restrict__ fc1w, const float* __restrict__ fc1b,
    const float* __restrict__ fc2w, const float* __restrict__ fc2b,
    float* __restrict__ logits) {
  int b = blockIdx.x;
  int t = threadIdx.x;
  __shared__ float p[192];
  __shared__ float hbuf[32];
  float inv = 1.0f / fmaxf(cnt[b], 1.0f);
  for (int i = t; i < 192; i += 64) p[i] = pooled[b * 192 + i] * inv;
  __syncthreads();
  if (t < 32) {
    float acc = fc1b[t];
    for (int i = 0; i < 192; i++) acc = fmaf(p[i], fc1w[i * 32 + t], acc);
    hbuf[t] = fmaxf(acc, 0.f);
  }
  __syncthreads();
  if (t < 2) {
    float acc = fc2b[t];
    for (int j = 0; j < 32; j++) acc = fmaf(hbuf[j], fc2w[j * 2 + t], acc);
    logits[b * 2 + t] = acc;
  }
}

static inline int divup(int a, int b) { return (a + b - 1) / b; }

extern "C" void kernel_launch(void* const* d_in, const int* in_sizes, int n_in,
                              void* d_out, int out_size, void* d_ws, size_t ws_size,
                              hipStream_t stream) {
  const int N = 20000, E = 320000, B = 64;
  const float* x     = (const float*)d_in[0];
  const int*   ei    = (const int*)d_in[1];
  const float* eattr = (const float*)d_in[2];
  const int*   batch = (const int*)d_in[3];
  const int* srcp = ei;
  const int* dstp = ei + E;

  const float* Wq[3]; const float* bq[3]; const float* Wk[3]; const float* bk[3];
  const float* Wv[3]; const float* bv[3]; const float* We[3]; const float* Ws[3];
  const float* bs[3];
  for (int l = 0; l < 3; l++) {
    int base = 4 + l * 9;
    Wq[l] = (const float*)d_in[base + 0]; bq[l] = (const float*)d_in[base + 1];
    Wk[l] = (const float*)d_in[base + 2]; bk[l] = (const float*)d_in[base + 3];
    Wv[l] = (const float*)d_in[base + 4]; bv[l] = (const float*)d_in[base + 5];
    We[l] = (const float*)d_in[base + 6];
    Ws[l] = (const float*)d_in[base + 7]; bs[l] = (const float*)d_in[base + 8];
  }
  const float* g1  = (const float*)d_in[31]; const float* be1 = (const float*)d_in[32];
  const float* g2  = (const float*)d_in[33]; const float* be2 = (const float*)d_in[34];
  const float* fc1w = (const float*)d_in[35]; const float* fc1b = (const float*)d_in[36];
  const float* fc2w = (const float*)d_in[37]; const float* fc2b = (const float*)d_in[38];

  float* out = (float*)d_out;
  float* logits = out;
  float* a1 = out + 128;
  float* a2 = a1 + (size_t)E * 4;
  float* a3 = a2 + (size_t)E * 4;

  float* ws = (float*)d_ws;
  size_t o = 0;
  float* qb = ws + o; o += (size_t)N * 256;
  float* kb = ws + o; o += (size_t)N * 256;
  float* vb = ws + o; o += (size_t)N * 256;
  float* xa = ws + o; o += (size_t)N * 256;
  float* xb = ws + o; o += (size_t)N * 256;
  float* sc = ws + o; o += (size_t)E * 6;
  int*   cntb  = (int*)(ws + o); o += N;
  int*   startb= (int*)(ws + o); o += N + 1;
  int*   offb  = (int*)(ws + o); o += N + 1;
  int*   src_s = (int*)(ws + o); o += E;
  float* ea_s  = ws + o; o += E;
  int*   eid_s = (int*)(ws + o); o += E;
  float* pooled = ws + o; o += (size_t)B * 192;
  float* cnt    = ws + o; o += B;
  unsigned short* Ah = (unsigned short*)(ws + o); o += (size_t)N * 128;
  unsigned short* Al = (unsigned short*)(ws + o); o += (size_t)N * 128;
  unsigned short* Wh12 = (unsigned short*)(ws + o); o += (size_t)12 * 32768;
  unsigned short* Wl12 = (unsigned short*)(ws + o); o += (size_t)12 * 32768;

  dim3 blk(256);

  struct LayerCfg { int K, M; float scale; };
  LayerCfg cfg[3] = {
    {192, 256, 0.125f},
    {256, 256, 0.125f},
    {256, 192, 0.1767766952966369f},
  };
  const float* Wmats[12];
  for (int l = 0; l < 3; l++) {
    Wmats[l * 4 + 0] = Wq[l]; Wmats[l * 4 + 1] = Wk[l];
    Wmats[l * 4 + 2] = Wv[l]; Wmats[l * 4 + 3] = Ws[l];
  }
  for (int i = 0; i < 12; i++) {
    int l = i / 4;
    int KM = cfg[l].K * cfg[l].M;
    cvt_w<<<divup(KM, 256), blk, 0, stream>>>(Wmats[i], Wh12 + (size_t)i * 65536,
                                              Wl12 + (size_t)i * 65536, cfg[l].K, cfg[l].M);
  }

  // ---- counting sort of edges by dst ----
  fill_i32<<<divup(N, 256), blk, 0, stream>>>(cntb, 0, N);
  hist_dst<<<divup(E, 256), blk, 0, stream>>>(dstp, cntb, E);
  scan_hist<<<1, dim3(1024), 0, stream>>>(cntb, startb, offb, N);
  scatter_edges<<<divup(E, 256), blk, 0, stream>>>(srcp, dstp, eattr, offb,
                                                  src_s, ea_s, eid_s, E);

  const float* lin_in[3]  = {x, xa, xb};
  float*       lay_out[3] = {xa, xb, xa};
  float*       alpha_out[3] = {a1, a2, a3};

  for (int l = 0; l < 3; l++) {
    int K = cfg[l].K, M = cfg[l].M;
    cvt_split<<<divup(N * K, 256), blk, 0, stream>>>(lin_in[l], Ah, Al, N * K);
    GemmArgs ga;
    float* outs[4] = {qb, kb, vb, lay_out[l]};
    const float* biases[4] = {bq[l], bk[l], bv[l], bs[l]};
    for (int z = 0; z < 4; z++) {
      ga.Wh[z] = Wh12 + (size_t)(l * 4 + z) * 65536;
      ga.Wl[z] = Wl12 + (size_t)(l * 4 + z) * 65536;
      ga.bias[z] = biases[z];
      ga.out[z] = outs[z];
    }
    dim3 gg(divup(N, 64));
    if (l == 0)      gemm4_reg<6, 4><<<gg, blk, 0, stream>>>(Ah, Al, ga, N, K, M);
    else if (l == 1) gemm4_reg<8, 4><<<gg, blk, 0, stream>>>(Ah, Al, ga, N, K, M);
    else             gemm4_reg<8, 3><<<gg, blk, 0, stream>>>(Ah, Al, ga, N, K, M);

    dim3 gat(divup(N * 64, 256));
    if (l < 2) {
      attn_fused<4, 16><<<gat, blk, 0, stream>>>(qb, kb, vb, We[l], startb, src_s,
                                                 ea_s, eid_s, sc, lay_out[l],
                                                 alpha_out[l], N, cfg[l].scale);
    } else {
      attn_fused<6, 8><<<gat, blk, 0, stream>>>(qb, kb, vb, We[l], startb, src_s,
                                                ea_s, eid_s, sc, lay_out[l],
                                                alpha_out[l], N, cfg[l].scale);
    }
    if (l == 0) ln_relu<<<divup(N, 4), blk, 0, stream>>>(xa, g1, be1, xa, N);
    if (l == 1) ln_relu<<<divup(N, 4), blk, 0, stream>>>(xb, g2, be2, xb, N);
  }

  fill_i32<<<divup(B * 192 + B, 256), blk, 0, stream>>>((int*)pooled, 0, B * 192 + B);
  resid_pool2<<<divup(N, 128), dim3(192), 0, stream>>>(x, xa, batch, pooled, cnt, N, 128);
  head_mlp<<<B, dim3(64), 0, stream>>>(pooled, cnt, fc1w, fc1b, fc2w, fc2b, logits);
}

// Round 5
// 1094.792 us; speedup vs baseline: 1.1282x; 1.1282x over previous
//
#include <hip/hip_runtime.h>
#include <cstdint>
#include <cstddef>

#define DEVINL __device__ __forceinline__

typedef short s16x8 __attribute__((ext_vector_type(8)));   // 8 bf16 in 4 VGPRs
typedef float f32x4 __attribute__((ext_vector_type(4)));

DEVINL unsigned short f2bf(float f) {
  unsigned u = __float_as_uint(f);
  unsigned r = (u + 0x7FFFu + ((u >> 16) & 1u)) >> 16;
  return (unsigned short)r;
}
DEVINL float bf2f(unsigned short b) { return __uint_as_float(((unsigned)b) << 16); }

__global__ __launch_bounds__(256) void fill_i32(int* __restrict__ p, int val, int n) {
  int i = blockIdx.x * 256 + threadIdx.x;
  if (i < n) p[i] = val;
}

// ---------------- bf16 hi/lo split conversions ----------------

__global__ __launch_bounds__(256) void cvt_split(const float* __restrict__ in,
                                                 unsigned short* __restrict__ hi,
                                                 unsigned short* __restrict__ lo, int n) {
  int i = blockIdx.x * 256 + threadIdx.x;
  if (i >= n) return;
  float f = in[i];
  unsigned short h = f2bf(f);
  float r = f - bf2f(h);
  hi[i] = h;
  lo[i] = f2bf(r);
}

// W[K,M] fp32 -> Wt_hi/lo[M,K] bf16 (transposed for contiguous B fragments)
__global__ __launch_bounds__(256) void cvt_w(const float* __restrict__ W,
                                             unsigned short* __restrict__ Wh,
                                             unsigned short* __restrict__ Wl,
                                             int K, int M) {
  int i = blockIdx.x * 256 + threadIdx.x;
  if (i >= K * M) return;
  int k = i / M, m = i - k * M;
  float f = W[i];
  unsigned short h = f2bf(f);
  float r = f - bf2f(h);
  Wh[(size_t)m * K + k] = h;
  Wl[(size_t)m * K + k] = f2bf(r);
}

// ---------------- A-resident fused 4-matrix MFMA GEMM (bf16x3) -------
// grid (rowblocks, 8): blockIdx.y -> (z = y>>1, col-half = y&1).
// One wave owns 16 rows; A frags for the whole K in registers; W streams from L2.
struct GemmArgs {
  const unsigned short* Wh[4];
  const unsigned short* Wl[4];
  const float* bias[4];
  float* out[4];
};

template <int KC, int MT>   // KC = K/32, MT = M/64
__global__ __launch_bounds__(256) void gemm4_reg(
    const unsigned short* __restrict__ Ah, const unsigned short* __restrict__ Al,
    GemmArgs args, int N, int K, int M) {
  int wave = threadIdx.x >> 6;
  int lane = threadIdx.x & 63;
  int lrow = lane & 15;
  int quad = lane >> 4;
  int z = blockIdx.y >> 1;
  int half = blockIdx.y & 1;
  int row = blockIdx.x * 64 + wave * 16 + lrow;
  int arow = row < N ? row : N - 1;          // clamp: stays in-bounds, garbage OK
  size_t abase = (size_t)arow * K + quad * 8;
  s16x8 a_h[KC], a_l[KC];
#pragma unroll
  for (int kc = 0; kc < KC; kc++) {
    a_h[kc] = *(const s16x8*)(Ah + abase + kc * 32);
    a_l[kc] = *(const s16x8*)(Al + abase + kc * 32);
  }
  int rbase = blockIdx.x * 64 + wave * 16 + quad * 4;
  const unsigned short* __restrict__ Wh = args.Wh[z];
  const unsigned short* __restrict__ Wl = args.Wl[z];
  const float* __restrict__ bias = args.bias[z];
  float* __restrict__ C = args.out[z];
  const int CGH = MT * 2;                    // col-groups per half
#pragma unroll 2
  for (int cgi = 0; cgi < CGH; cgi++) {
    int cg = half * CGH + cgi;
    int col = cg * 16 + lrow;
    size_t wbase = (size_t)col * K + quad * 8;
    f32x4 acc = {};
#pragma unroll
    for (int kc = 0; kc < KC; kc++) {
      s16x8 w_h = *(const s16x8*)(Wh + wbase + kc * 32);
      s16x8 w_l = *(const s16x8*)(Wl + wbase + kc * 32);
      acc = __builtin_amdgcn_mfma_f32_16x16x32_bf16(a_h[kc], w_h, acc, 0, 0, 0);
      acc = __builtin_amdgcn_mfma_f32_16x16x32_bf16(a_l[kc], w_h, acc, 0, 0, 0);
      acc = __builtin_amdgcn_mfma_f32_16x16x32_bf16(a_h[kc], w_l, acc, 0, 0, 0);
    }
    float bv = bias[col];
#pragma unroll
    for (int r = 0; r < 4; r++) {
      int rr = rbase + r;
      if (rr < N) C[(size_t)rr * M + col] = acc[r] + bv;
    }
  }
}

// ---------------- counting sort of edges by dst ----------------

__global__ __launch_bounds__(256) void hist_dst(const int* __restrict__ dst,
                                                int* __restrict__ cnt, int E) {
  int e = blockIdx.x * 256 + threadIdx.x;
  if (e < E) atomicAdd(&cnt[dst[e] + 1], 1);
}

__global__ __launch_bounds__(1024) void scan_hist(const int* __restrict__ cnt,
                                                  int* __restrict__ start,
                                                  int* __restrict__ off, int N) {
  __shared__ int sums[1024];
  const int CH = 20;
  int t = threadIdx.x;
  int base = t * CH;
  int local[CH];
  int tot = 0;
  if (base < N) {
#pragma unroll
    for (int i = 0; i < CH; i++) { local[i] = cnt[base + i]; tot += local[i]; }
  }
  sums[t] = tot;
  __syncthreads();
  for (int d = 1; d < 1024; d <<= 1) {
    int v = (t >= d) ? sums[t - d] : 0;
    __syncthreads();
    sums[t] += v;
    __syncthreads();
  }
  if (base < N) {
    int run = (t == 0) ? 0 : sums[t - 1];
#pragma unroll
    for (int i = 0; i < CH; i++) { start[base + i] = run; off[base + i] = run; run += local[i]; }
    if (base + CH == N) start[N] = run;
  }
}

__global__ __launch_bounds__(256) void scatter_edges(
    const int* __restrict__ src, const int* __restrict__ dst,
    const float* __restrict__ ea, int* __restrict__ off,
    int* __restrict__ src_s, float* __restrict__ ea_s, int* __restrict__ eid_s, int E) {
  int e = blockIdx.x * 256 + threadIdx.x;
  if (e >= E) return;
  int d = dst[e] + 1;
  int pos = atomicAdd(&off[d], 1);
  src_s[pos] = src[e] + 1;
  ea_s[pos] = ea[e];
  eid_s[pos] = e;
}

// ---------------- fused per-dst attention (flash-style) ----------------
template <int H, int LPH>
__global__ __launch_bounds__(256) void attn_fused(
    const float* __restrict__ q, const float* __restrict__ k,
    const float* __restrict__ v, const float* __restrict__ We,
    const int* __restrict__ start, const int* __restrict__ src_s,
    const float* __restrict__ ea_s, const int* __restrict__ eid_s,
    float* __restrict__ sc, float* __restrict__ outp,
    float* __restrict__ alpha, int Nn, float scale) {
  const int HC = H * LPH * 4;
  int w = (blockIdx.x * 256 + threadIdx.x) >> 6;
  int lane = threadIdx.x & 63;
  if (w >= Nn) return;
  int b = start[w], e = start[w + 1];
  if (b == e) return;
  bool act = lane < H * LPH;
  int idx = lane * 4;
  int head = lane / LPH;
  float4 q4 = make_float4(0.f, 0.f, 0.f, 0.f), We4 = q4;
  if (act) {
    q4 = *(const float4*)(q + (size_t)w * HC + idx);
    We4 = *(const float4*)(We + idx);
  }
  float m = -INFINITY, l = 0.f;
  float4 acc = make_float4(0.f, 0.f, 0.f, 0.f);
  for (int pos = b; pos < e; pos++) {
    int s = src_s[pos];
    float eav = ea_s[pos];
    float4 k4 = make_float4(0.f, 0.f, 0.f, 0.f);
    float4 v4 = k4;
    if (act) {
      k4 = *(const float4*)(k + (size_t)s * HC + idx);
      v4 = *(const float4*)(v + (size_t)s * HC + idx);
    }
    k4.x = fmaf(eav, We4.x, k4.x); k4.y = fmaf(eav, We4.y, k4.y);
    k4.z = fmaf(eav, We4.z, k4.z); k4.w = fmaf(eav, We4.w, k4.w);
    v4.x = fmaf(eav, We4.x, v4.x); v4.y = fmaf(eav, We4.y, v4.y);
    v4.z = fmaf(eav, We4.z, v4.z); v4.w = fmaf(eav, We4.w, v4.w);
    float p = q4.x * k4.x + q4.y * k4.y + q4.z * k4.z + q4.w * k4.w;
#pragma unroll
    for (int mm = 1; mm < LPH; mm <<= 1) p += __shfl_xor(p, mm, 64);
    float score = p * scale;
    if (act && (lane % LPH) == 0) sc[(size_t)pos * H + head] = score;
    float mn = fmaxf(m, score);
    float f = __expf(m - mn);
    float es = __expf(score - mn);
    l = l * f + es;
    m = mn;
    acc.x = fmaf(acc.x, f, es * v4.x);
    acc.y = fmaf(acc.y, f, es * v4.y);
    acc.z = fmaf(acc.z, f, es * v4.z);
    acc.w = fmaf(acc.w, f, es * v4.w);
  }
  float invl = 1.0f / (l + 1e-16f);
  if (act) {
    float* orow = outp + (size_t)w * HC + idx;
    float4 o = *(float4*)orow;
    o.x += acc.x * invl; o.y += acc.y * invl;
    o.z += acc.z * invl; o.w += acc.w * invl;
    *(float4*)orow = o;
  }
  for (int pos = b; pos < e; pos++) {
    if (act && (lane % LPH) == 0) {
      float sv = sc[(size_t)pos * H + head];
      alpha[(size_t)eid_s[pos] * H + head] = __expf(sv - m) * invl;
    }
  }
}

// ---------------- misc dense kernels ----------------

__global__ __launch_bounds__(256) void ln_relu(
    const float* __restrict__ in, const float* __restrict__ g,
    const float* __restrict__ b, float* __restrict__ o, int N) {
  int w = (blockIdx.x * 256 + threadIdx.x) >> 6;
  int lane = threadIdx.x & 63;
  if (w >= N) return;
  float4 x = *(const float4*)(in + (size_t)w * 256 + lane * 4);
  float s = x.x + x.y + x.z + x.w;
  float s2 = x.x * x.x + x.y * x.y + x.z * x.z + x.w * x.w;
  for (int m = 1; m < 64; m <<= 1) { s += __shfl_xor(s, m, 64); s2 += __shfl_xor(s2, m, 64); }
  float mu = s * (1.0f / 256.0f);
  float var = s2 * (1.0f / 256.0f) - mu * mu;
  float inv = rsqrtf(var + 1e-5f);
  float4 gv = *(const float4*)(g + lane * 4);
  float4 bv = *(const float4*)(b + lane * 4);
  float4 y;
  y.x = fmaxf(fmaf((x.x - mu) * inv, gv.x, bv.x), 0.f);
  y.y = fmaxf(fmaf((x.y - mu) * inv, gv.y, bv.y), 0.f);
  y.z = fmaxf(fmaf((x.z - mu) * inv, gv.z, bv.z), 0.f);
  y.w = fmaxf(fmaf((x.w - mu) * inv, gv.w, bv.w), 0.f);
  *(float4*)(o + (size_t)w * 256 + lane * 4) = y;
}

__global__ __launch_bounds__(192) void resid_pool2(
    const float* __restrict__ x, const float* __restrict__ x3,
    const int* __restrict__ batch, float* __restrict__ pooled,
    float* __restrict__ cnt, int N, int R) {
  int col = threadIdx.x;  // 0..191
  int r0 = blockIdx.x * R;
  int r1 = min(r0 + R, N);
  if (r0 >= N) return;
  float acc = 0.f;
  int cur = batch[r0];
  int run = 0;
  for (int r = r0; r < r1; r++) {
    int b = batch[r];
    if (b != cur) {
      atomicAdd(&pooled[cur * 192 + col], acc);
      if (col == 0) atomicAdd(&cnt[cur], (float)run);
      acc = 0.f; run = 0; cur = b;
    }
    size_t i = (size_t)r * 192 + col;
    acc += x[i] + fmaxf(x3[i], 0.f);
    run++;
  }
  atomicAdd(&pooled[cur * 192 + col], acc);
  if (col == 0) atomicAdd(&cnt[cur], (float)run);
}

__global__ __launch_bounds__(64) void head_mlp(
    const float* __restrict__ pooled, const float* __restrict__ cnt,
    const float* __restrict__ fc1w, const float* __restrict__ fc1b,
    const float* __restrict__ fc2w, const float* __restrict__ fc2b,
    float* __restrict__ logits) {
  int b = blockIdx.x;
  int t = threadIdx.x;
  __shared__ float p[192];
  __shared__ float hbuf[32];
  float inv = 1.0f / fmaxf(cnt[b], 1.0f);
  for (int i = t; i < 192; i += 64) p[i] = pooled[b * 192 + i] * inv;
  __syncthreads();
  if (t < 32) {
    float acc = fc1b[t];
    for (int i = 0; i < 192; i++) acc = fmaf(p[i], fc1w[i * 32 + t], acc);
    hbuf[t] = fmaxf(acc, 0.f);
  }
  __syncthreads();
  if (t < 2) {
    float acc = fc2b[t];
    for (int j = 0; j < 32; j++) acc = fmaf(hbuf[j], fc2w[j * 2 + t], acc);
    logits[b * 2 + t] = acc;
  }
}

static inline int divup(int a, int b) { return (a + b - 1) / b; }

extern "C" void kernel_launch(void* const* d_in, const int* in_sizes, int n_in,
                              void* d_out, int out_size, void* d_ws, size_t ws_size,
                              hipStream_t stream) {
  const int N = 20000, E = 320000, B = 64;
  const float* x     = (const float*)d_in[0];
  const int*   ei    = (const int*)d_in[1];
  const float* eattr = (const float*)d_in[2];
  const int*   batch = (const int*)d_in[3];
  const int* srcp = ei;
  const int* dstp = ei + E;

  const float* Wq[3]; const float* bq[3]; const float* Wk[3]; const float* bk[3];
  const float* Wv[3]; const float* bv[3]; const float* We[3]; const float* Ws[3];
  const float* bs[3];
  for (int l = 0; l < 3; l++) {
    int base = 4 + l * 9;
    Wq[l] = (const float*)d_in[base + 0]; bq[l] = (const float*)d_in[base + 1];
    Wk[l] = (const float*)d_in[base + 2]; bk[l] = (const float*)d_in[base + 3];
    Wv[l] = (const float*)d_in[base + 4]; bv[l] = (const float*)d_in[base + 5];
    We[l] = (const float*)d_in[base + 6];
    Ws[l] = (const float*)d_in[base + 7]; bs[l] = (const float*)d_in[base + 8];
  }
  const float* g1  = (const float*)d_in[31]; const float* be1 = (const float*)d_in[32];
  const float* g2  = (const float*)d_in[33]; const float* be2 = (const float*)d_in[34];
  const float* fc1w = (const float*)d_in[35]; const float* fc1b = (const float*)d_in[36];
  const float* fc2w = (const float*)d_in[37]; const float* fc2b = (const float*)d_in[38];

  float* out = (float*)d_out;
  float* logits = out;
  float* a1 = out + 128;
  float* a2 = a1 + (size_t)E * 4;
  float* a3 = a2 + (size_t)E * 4;

  float* ws = (float*)d_ws;
  size_t o = 0;
  float* qb = ws + o; o += (size_t)N * 256;
  float* kb = ws + o; o += (size_t)N * 256;
  float* vb = ws + o; o += (size_t)N * 256;
  float* xa = ws + o; o += (size_t)N * 256;
  float* xb = ws + o; o += (size_t)N * 256;
  float* sc = ws + o; o += (size_t)E * 6;
  int*   cntb  = (int*)(ws + o); o += N;
  int*   startb= (int*)(ws + o); o += N + 1;
  int*   offb  = (int*)(ws + o); o += N + 1;
  int*   src_s = (int*)(ws + o); o += E;
  float* ea_s  = ws + o; o += E;
  int*   eid_s = (int*)(ws + o); o += E;
  float* pooled = ws + o; o += (size_t)B * 192;
  float* cnt    = ws + o; o += B;
  unsigned short* Ah = (unsigned short*)(ws + o); o += (size_t)N * 128;
  unsigned short* Al = (unsigned short*)(ws + o); o += (size_t)N * 128;
  unsigned short* Wh12 = (unsigned short*)(ws + o); o += (size_t)12 * 32768;
  unsigned short* Wl12 = (unsigned short*)(ws + o); o += (size_t)12 * 32768;

  dim3 blk(256);

  struct LayerCfg { int K, M; float scale; };
  LayerCfg cfg[3] = {
    {192, 256, 0.125f},
    {256, 256, 0.125f},
    {256, 192, 0.1767766952966369f},
  };
  const float* Wmats[12];
  for (int l = 0; l < 3; l++) {
    Wmats[l * 4 + 0] = Wq[l]; Wmats[l * 4 + 1] = Wk[l];
    Wmats[l * 4 + 2] = Wv[l]; Wmats[l * 4 + 3] = Ws[l];
  }
  for (int i = 0; i < 12; i++) {
    int l = i / 4;
    int KM = cfg[l].K * cfg[l].M;
    cvt_w<<<divup(KM, 256), blk, 0, stream>>>(Wmats[i], Wh12 + (size_t)i * 65536,
                                              Wl12 + (size_t)i * 65536, cfg[l].K, cfg[l].M);
  }

  // ---- counting sort of edges by dst ----
  fill_i32<<<divup(N, 256), blk, 0, stream>>>(cntb, 0, N);
  hist_dst<<<divup(E, 256), blk, 0, stream>>>(dstp, cntb, E);
  scan_hist<<<1, dim3(1024), 0, stream>>>(cntb, startb, offb, N);
  scatter_edges<<<divup(E, 256), blk, 0, stream>>>(srcp, dstp, eattr, offb,
                                                  src_s, ea_s, eid_s, E);

  const float* lin_in[3]  = {x, xa, xb};
  float*       lay_out[3] = {xa, xb, xa};
  float*       alpha_out[3] = {a1, a2, a3};

  for (int l = 0; l < 3; l++) {
    int K = cfg[l].K, M = cfg[l].M;
    cvt_split<<<divup(N * K, 256), blk, 0, stream>>>(lin_in[l], Ah, Al, N * K);
    GemmArgs ga;
    float* outs[4] = {qb, kb, vb, lay_out[l]};
    const float* biases[4] = {bq[l], bk[l], bv[l], bs[l]};
    for (int z = 0; z < 4; z++) {
      ga.Wh[z] = Wh12 + (size_t)(l * 4 + z) * 65536;
      ga.Wl[z] = Wl12 + (size_t)(l * 4 + z) * 65536;
      ga.bias[z] = biases[z];
      ga.out[z] = outs[z];
    }
    dim3 gg(divup(N, 64), 8);
    if (l == 0)      gemm4_reg<6, 4><<<gg, blk, 0, stream>>>(Ah, Al, ga, N, K, M);
    else if (l == 1) gemm4_reg<8, 4><<<gg, blk, 0, stream>>>(Ah, Al, ga, N, K, M);
    else             gemm4_reg<8, 3><<<gg, blk, 0, stream>>>(Ah, Al, ga, N, K, M);

    dim3 gat(divup(N * 64, 256));
    if (l < 2) {
      attn_fused<4, 16><<<gat, blk, 0, stream>>>(qb, kb, vb, We[l], startb, src_s,
                                                 ea_s, eid_s, sc, lay_out[l],
                                                 alpha_out[l], N, cfg[l].scale);
    } else {
      attn_fused<6, 8><<<gat, blk, 0, stream>>>(qb, kb, vb, We[l], startb, src_s,
                                                ea_s, eid_s, sc, lay_out[l],
                                                alpha_out[l], N, cfg[l].scale);
    }
    if (l == 0) ln_relu<<<divup(N, 4), blk, 0, stream>>>(xa, g1, be1, xa, N);
    if (l == 1) ln_relu<<<divup(N, 4), blk, 0, stream>>>(xb, g2, be2, xb, N);
  }

  fill_i32<<<divup(B * 192 + B, 256), blk, 0, stream>>>((int*)pooled, 0, B * 192 + B);
  resid_pool2<<<divup(N, 128), dim3(192), 0, stream>>>(x, xa, batch, pooled, cnt, N, 128);
  head_mlp<<<B, dim3(64), 0, stream>>>(pooled, cnt, fc1w, fc1b, fc2w, fc2b, logits);
}

// Round 6
// 1070.615 us; speedup vs baseline: 1.1536x; 1.0226x over previous
//
#include <hip/hip_runtime.h>
#include <cstdint>
#include <cstddef>

#define DEVINL __device__ __forceinline__

typedef short s16x8 __attribute__((ext_vector_type(8)));   // 8 bf16 in 4 VGPRs
typedef float f32x4 __attribute__((ext_vector_type(4)));

DEVINL unsigned short f2bf(float f) {
  unsigned u = __float_as_uint(f);
  unsigned r = (u + 0x7FFFu + ((u >> 16) & 1u)) >> 16;
  return (unsigned short)r;
}
DEVINL float bf2f(unsigned short b) { return __uint_as_float(((unsigned)b) << 16); }

__global__ __launch_bounds__(256) void fill_i32(int* __restrict__ p, int val, int n) {
  int i = blockIdx.x * 256 + threadIdx.x;
  if (i < n) p[i] = val;
}

// ---------------- bf16 hi/lo split conversions ----------------

__global__ __launch_bounds__(256) void cvt_split(const float* __restrict__ in,
                                                 unsigned short* __restrict__ hi,
                                                 unsigned short* __restrict__ lo, int n) {
  int i = blockIdx.x * 256 + threadIdx.x;
  if (i >= n) return;
  float f = in[i];
  unsigned short h = f2bf(f);
  float r = f - bf2f(h);
  hi[i] = h;
  lo[i] = f2bf(r);
}

// W[K,M] fp32 -> Wt_hi/lo[M,K] bf16 (transposed for contiguous B fragments)
__global__ __launch_bounds__(256) void cvt_w(const float* __restrict__ W,
                                             unsigned short* __restrict__ Wh,
                                             unsigned short* __restrict__ Wl,
                                             int K, int M) {
  int i = blockIdx.x * 256 + threadIdx.x;
  if (i >= K * M) return;
  int k = i / M, m = i - k * M;
  float f = W[i];
  unsigned short h = f2bf(f);
  float r = f - bf2f(h);
  Wh[(size_t)m * K + k] = h;
  Wl[(size_t)m * K + k] = f2bf(r);
}

// ---------------- A-resident fused 4-matrix MFMA GEMM (bf16x3) -------
// grid (rowblocks, 8): blockIdx.y -> (z = y>>1, col-half = y&1).
// One wave owns 16 rows; A frags for the whole K in registers; W streams from L2.
// __launch_bounds__(256, 4): VGPR cap 128 — A frags (64 VGPR) MUST NOT spill.
// (R4's bare launch_bounds gave a 64-VGPR budget -> A spilled to scratch ->
//  ~6000 cyc/col-group scratch-reload stalls, MfmaUtil 6%.)
struct GemmArgs {
  const unsigned short* Wh[4];
  const unsigned short* Wl[4];
  const float* bias[4];
  float* out[4];
};

template <int KC, int MT>   // KC = K/32, MT = M/64
__global__ __launch_bounds__(256, 4) void gemm4_reg(
    const unsigned short* __restrict__ Ah, const unsigned short* __restrict__ Al,
    GemmArgs args, int N, int K, int M) {
  int wave = threadIdx.x >> 6;
  int lane = threadIdx.x & 63;
  int lrow = lane & 15;
  int quad = lane >> 4;
  int z = blockIdx.y >> 1;
  int half = blockIdx.y & 1;
  int row = blockIdx.x * 64 + wave * 16 + lrow;
  int arow = row < N ? row : N - 1;          // clamp: stays in-bounds, garbage OK
  size_t abase = (size_t)arow * K + quad * 8;
  s16x8 a_h[KC], a_l[KC];
#pragma unroll
  for (int kc = 0; kc < KC; kc++) {
    a_h[kc] = *(const s16x8*)(Ah + abase + kc * 32);
    a_l[kc] = *(const s16x8*)(Al + abase + kc * 32);
  }
  int rbase = blockIdx.x * 64 + wave * 16 + quad * 4;
  const unsigned short* __restrict__ Wh = args.Wh[z];
  const unsigned short* __restrict__ Wl = args.Wl[z];
  const float* __restrict__ bias = args.bias[z];
  float* __restrict__ C = args.out[z];
  const int CGH = MT * 2;                    // col-groups per half
  for (int cgi = 0; cgi < CGH; cgi++) {
    int cg = half * CGH + cgi;
    int col = cg * 16 + lrow;
    size_t wbase = (size_t)col * K + quad * 8;
    f32x4 acc = {};
#pragma unroll
    for (int kc = 0; kc < KC; kc++) {
      s16x8 w_h = *(const s16x8*)(Wh + wbase + kc * 32);
      s16x8 w_l = *(const s16x8*)(Wl + wbase + kc * 32);
      acc = __builtin_amdgcn_mfma_f32_16x16x32_bf16(a_h[kc], w_h, acc, 0, 0, 0);
      acc = __builtin_amdgcn_mfma_f32_16x16x32_bf16(a_l[kc], w_h, acc, 0, 0, 0);
      acc = __builtin_amdgcn_mfma_f32_16x16x32_bf16(a_h[kc], w_l, acc, 0, 0, 0);
    }
    float bv = bias[col];
#pragma unroll
    for (int r = 0; r < 4; r++) {
      int rr = rbase + r;
      if (rr < N) C[(size_t)rr * M + col] = acc[r] + bv;
    }
  }
}

// ---------------- counting sort of edges by dst ----------------

__global__ __launch_bounds__(256) void hist_dst(const int* __restrict__ dst,
                                                int* __restrict__ cnt, int E) {
  int e = blockIdx.x * 256 + threadIdx.x;
  if (e < E) atomicAdd(&cnt[dst[e] + 1], 1);
}

__global__ __launch_bounds__(1024) void scan_hist(const int* __restrict__ cnt,
                                                  int* __restrict__ start,
                                                  int* __restrict__ off, int N) {
  __shared__ int sums[1024];
  const int CH = 20;
  int t = threadIdx.x;
  int base = t * CH;
  int local[CH];
  int tot = 0;
  if (base < N) {
#pragma unroll
    for (int i = 0; i < CH; i++) { local[i] = cnt[base + i]; tot += local[i]; }
  }
  sums[t] = tot;
  __syncthreads();
  for (int d = 1; d < 1024; d <<= 1) {
    int v = (t >= d) ? sums[t - d] : 0;
    __syncthreads();
    sums[t] += v;
    __syncthreads();
  }
  if (base < N) {
    int run = (t == 0) ? 0 : sums[t - 1];
#pragma unroll
    for (int i = 0; i < CH; i++) { start[base + i] = run; off[base + i] = run; run += local[i]; }
    if (base + CH == N) start[N] = run;
  }
}

__global__ __launch_bounds__(256) void scatter_edges(
    const int* __restrict__ src, const int* __restrict__ dst,
    const float* __restrict__ ea, int* __restrict__ off,
    int* __restrict__ src_s, float* __restrict__ ea_s, int* __restrict__ eid_s, int E) {
  int e = blockIdx.x * 256 + threadIdx.x;
  if (e >= E) return;
  int d = dst[e] + 1;
  int pos = atomicAdd(&off[d], 1);
  src_s[pos] = src[e] + 1;
  ea_s[pos] = ea[e];
  eid_s[pos] = e;
}

// ---------------- fused per-dst attention (flash-style) ----------------
template <int H, int LPH>
__global__ __launch_bounds__(256) void attn_fused(
    const float* __restrict__ q, const float* __restrict__ k,
    const float* __restrict__ v, const float* __restrict__ We,
    const int* __restrict__ start, const int* __restrict__ src_s,
    const float* __restrict__ ea_s, const int* __restrict__ eid_s,
    float* __restrict__ sc, float* __restrict__ outp,
    float* __restrict__ alpha, int Nn, float scale) {
  const int HC = H * LPH * 4;
  int w = (blockIdx.x * 256 + threadIdx.x) >> 6;
  int lane = threadIdx.x & 63;
  if (w >= Nn) return;
  int b = start[w], e = start[w + 1];
  if (b == e) return;
  bool act = lane < H * LPH;
  int idx = lane * 4;
  int head = lane / LPH;
  float4 q4 = make_float4(0.f, 0.f, 0.f, 0.f), We4 = q4;
  if (act) {
    q4 = *(const float4*)(q + (size_t)w * HC + idx);
    We4 = *(const float4*)(We + idx);
  }
  float m = -INFINITY, l = 0.f;
  float4 acc = make_float4(0.f, 0.f, 0.f, 0.f);
  for (int pos = b; pos < e; pos++) {
    int s = src_s[pos];
    float eav = ea_s[pos];
    float4 k4 = make_float4(0.f, 0.f, 0.f, 0.f);
    float4 v4 = k4;
    if (act) {
      k4 = *(const float4*)(k + (size_t)s * HC + idx);
      v4 = *(const float4*)(v + (size_t)s * HC + idx);
    }
    k4.x = fmaf(eav, We4.x, k4.x); k4.y = fmaf(eav, We4.y, k4.y);
    k4.z = fmaf(eav, We4.z, k4.z); k4.w = fmaf(eav, We4.w, k4.w);
    v4.x = fmaf(eav, We4.x, v4.x); v4.y = fmaf(eav, We4.y, v4.y);
    v4.z = fmaf(eav, We4.z, v4.z); v4.w = fmaf(eav, We4.w, v4.w);
    float p = q4.x * k4.x + q4.y * k4.y + q4.z * k4.z + q4.w * k4.w;
#pragma unroll
    for (int mm = 1; mm < LPH; mm <<= 1) p += __shfl_xor(p, mm, 64);
    float score = p * scale;
    if (act && (lane % LPH) == 0) sc[(size_t)pos * H + head] = score;
    float mn = fmaxf(m, score);
    float f = __expf(m - mn);
    float es = __expf(score - mn);
    l = l * f + es;
    m = mn;
    acc.x = fmaf(acc.x, f, es * v4.x);
    acc.y = fmaf(acc.y, f, es * v4.y);
    acc.z = fmaf(acc.z, f, es * v4.z);
    acc.w = fmaf(acc.w, f, es * v4.w);
  }
  float invl = 1.0f / (l + 1e-16f);
  if (act) {
    float* orow = outp + (size_t)w * HC + idx;
    float4 o = *(float4*)orow;
    o.x += acc.x * invl; o.y += acc.y * invl;
    o.z += acc.z * invl; o.w += acc.w * invl;
    *(float4*)orow = o;
  }
  for (int pos = b; pos < e; pos++) {
    if (act && (lane % LPH) == 0) {
      float sv = sc[(size_t)pos * H + head];
      alpha[(size_t)eid_s[pos] * H + head] = __expf(sv - m) * invl;
    }
  }
}

// ---------------- misc dense kernels ----------------

__global__ __launch_bounds__(256) void ln_relu(
    const float* __restrict__ in, const float* __restrict__ g,
    const float* __restrict__ b, float* __restrict__ o, int N) {
  int w = (blockIdx.x * 256 + threadIdx.x) >> 6;
  int lane = threadIdx.x & 63;
  if (w >= N) return;
  float4 x = *(const float4*)(in + (size_t)w * 256 + lane * 4);
  float s = x.x + x.y + x.z + x.w;
  float s2 = x.x * x.x + x.y * x.y + x.z * x.z + x.w * x.w;
  for (int m = 1; m < 64; m <<= 1) { s += __shfl_xor(s, m, 64); s2 += __shfl_xor(s2, m, 64); }
  float mu = s * (1.0f / 256.0f);
  float var = s2 * (1.0f / 256.0f) - mu * mu;
  float inv = rsqrtf(var + 1e-5f);
  float4 gv = *(const float4*)(g + lane * 4);
  float4 bv = *(const float4*)(b + lane * 4);
  float4 y;
  y.x = fmaxf(fmaf((x.x - mu) * inv, gv.x, bv.x), 0.f);
  y.y = fmaxf(fmaf((x.y - mu) * inv, gv.y, bv.y), 0.f);
  y.z = fmaxf(fmaf((x.z - mu) * inv, gv.z, bv.z), 0.f);
  y.w = fmaxf(fmaf((x.w - mu) * inv, gv.w, bv.w), 0.f);
  *(float4*)(o + (size_t)w * 256 + lane * 4) = y;
}

__global__ __launch_bounds__(192) void resid_pool2(
    const float* __restrict__ x, const float* __restrict__ x3,
    const int* __restrict__ batch, float* __restrict__ pooled,
    float* __restrict__ cnt, int N, int R) {
  int col = threadIdx.x;  // 0..191
  int r0 = blockIdx.x * R;
  int r1 = min(r0 + R, N);
  if (r0 >= N) return;
  float acc = 0.f;
  int cur = batch[r0];
  int run = 0;
  for (int r = r0; r < r1; r++) {
    int b = batch[r];
    if (b != cur) {
      atomicAdd(&pooled[cur * 192 + col], acc);
      if (col == 0) atomicAdd(&cnt[cur], (float)run);
      acc = 0.f; run = 0; cur = b;
    }
    size_t i = (size_t)r * 192 + col;
    acc += x[i] + fmaxf(x3[i], 0.f);
    run++;
  }
  atomicAdd(&pooled[cur * 192 + col], acc);
  if (col == 0) atomicAdd(&cnt[cur], (float)run);
}

__global__ __launch_bounds__(64) void head_mlp(
    const float* __restrict__ pooled, const float* __restrict__ cnt,
    const float* __restrict__ fc1w, const float* __restrict__ fc1b,
    const float* __restrict__ fc2w, const float* __restrict__ fc2b,
    float* __restrict__ logits) {
  int b = blockIdx.x;
  int t = threadIdx.x;
  __shared__ float p[192];
  __shared__ float hbuf[32];
  float inv = 1.0f / fmaxf(cnt[b], 1.0f);
  for (int i = t; i < 192; i += 64) p[i] = pooled[b * 192 + i] * inv;
  __syncthreads();
  if (t < 32) {
    float acc = fc1b[t];
    for (int i = 0; i < 192; i++) acc = fmaf(p[i], fc1w[i * 32 + t], acc);
    hbuf[t] = fmaxf(acc, 0.f);
  }
  __syncthreads();
  if (t < 2) {
    float acc = fc2b[t];
    for (int j = 0; j < 32; j++) acc = fmaf(hbuf[j], fc2w[j * 2 + t], acc);
    logits[b * 2 + t] = acc;
  }
}

static inline int divup(int a, int b) { return (a + b - 1) / b; }

extern "C" void kernel_launch(void* const* d_in, const int* in_sizes, int n_in,
                              void* d_out, int out_size, void* d_ws, size_t ws_size,
                              hipStream_t stream) {
  const int N = 20000, E = 320000, B = 64;
  const float* x     = (const float*)d_in[0];
  const int*   ei    = (const int*)d_in[1];
  const float* eattr = (const float*)d_in[2];
  const int*   batch = (const int*)d_in[3];
  const int* srcp = ei;
  const int* dstp = ei + E;

  const float* Wq[3]; const float* bq[3]; const float* Wk[3]; const float* bk[3];
  const float* Wv[3]; const float* bv[3]; const float* We[3]; const float* Ws[3];
  const float* bs[3];
  for (int l = 0; l < 3; l++) {
    int base = 4 + l * 9;
    Wq[l] = (const float*)d_in[base + 0]; bq[l] = (const float*)d_in[base + 1];
    Wk[l] = (const float*)d_in[base + 2]; bk[l] = (const float*)d_in[base + 3];
    Wv[l] = (const float*)d_in[base + 4]; bv[l] = (const float*)d_in[base + 5];
    We[l] = (const float*)d_in[base + 6];
    Ws[l] = (const float*)d_in[base + 7]; bs[l] = (const float*)d_in[base + 8];
  }
  const float* g1  = (const float*)d_in[31]; const float* be1 = (const float*)d_in[32];
  const float* g2  = (const float*)d_in[33]; const float* be2 = (const float*)d_in[34];
  const float* fc1w = (const float*)d_in[35]; const float* fc1b = (const float*)d_in[36];
  const float* fc2w = (const float*)d_in[37]; const float* fc2b = (const float*)d_in[38];

  float* out = (float*)d_out;
  float* logits = out;
  float* a1 = out + 128;
  float* a2 = a1 + (size_t)E * 4;
  float* a3 = a2 + (size_t)E * 4;

  float* ws = (float*)d_ws;
  size_t o = 0;
  float* qb = ws + o; o += (size_t)N * 256;
  float* kb = ws + o; o += (size_t)N * 256;
  float* vb = ws + o; o += (size_t)N * 256;
  float* xa = ws + o; o += (size_t)N * 256;
  float* xb = ws + o; o += (size_t)N * 256;
  float* sc = ws + o; o += (size_t)E * 6;
  int*   cntb  = (int*)(ws + o); o += N;
  int*   startb= (int*)(ws + o); o += N + 1;
  int*   offb  = (int*)(ws + o); o += N + 1;
  int*   src_s = (int*)(ws + o); o += E;
  float* ea_s  = ws + o; o += E;
  int*   eid_s = (int*)(ws + o); o += E;
  float* pooled = ws + o; o += (size_t)B * 192;
  float* cnt    = ws + o; o += B;
  unsigned short* Ah = (unsigned short*)(ws + o); o += (size_t)N * 128;
  unsigned short* Al = (unsigned short*)(ws + o); o += (size_t)N * 128;
  unsigned short* Wh12 = (unsigned short*)(ws + o); o += (size_t)12 * 32768;
  unsigned short* Wl12 = (unsigned short*)(ws + o); o += (size_t)12 * 32768;

  dim3 blk(256);

  struct LayerCfg { int K, M; float scale; };
  LayerCfg cfg[3] = {
    {192, 256, 0.125f},
    {256, 256, 0.125f},
    {256, 192, 0.1767766952966369f},
  };
  const float* Wmats[12];
  for (int l = 0; l < 3; l++) {
    Wmats[l * 4 + 0] = Wq[l]; Wmats[l * 4 + 1] = Wk[l];
    Wmats[l * 4 + 2] = Wv[l]; Wmats[l * 4 + 3] = Ws[l];
  }
  for (int i = 0; i < 12; i++) {
    int l = i / 4;
    int KM = cfg[l].K * cfg[l].M;
    cvt_w<<<divup(KM, 256), blk, 0, stream>>>(Wmats[i], Wh12 + (size_t)i * 65536,
                                              Wl12 + (size_t)i * 65536, cfg[l].K, cfg[l].M);
  }

  // ---- counting sort of edges by dst ----
  fill_i32<<<divup(N, 256), blk, 0, stream>>>(cntb, 0, N);
  hist_dst<<<divup(E, 256), blk, 0, stream>>>(dstp, cntb, E);
  scan_hist<<<1, dim3(1024), 0, stream>>>(cntb, startb, offb, N);
  scatter_edges<<<divup(E, 256), blk, 0, stream>>>(srcp, dstp, eattr, offb,
                                                  src_s, ea_s, eid_s, E);

  const float* lin_in[3]  = {x, xa, xb};
  float*       lay_out[3] = {xa, xb, xa};
  float*       alpha_out[3] = {a1, a2, a3};

  for (int l = 0; l < 3; l++) {
    int K = cfg[l].K, M = cfg[l].M;
    cvt_split<<<divup(N * K, 256), blk, 0, stream>>>(lin_in[l], Ah, Al, N * K);
    GemmArgs ga;
    float* outs[4] = {qb, kb, vb, lay_out[l]};
    const float* biases[4] = {bq[l], bk[l], bv[l], bs[l]};
    for (int z = 0; z < 4; z++) {
      ga.Wh[z] = Wh12 + (size_t)(l * 4 + z) * 65536;
      ga.Wl[z] = Wl12 + (size_t)(l * 4 + z) * 65536;
      ga.bias[z] = biases[z];
      ga.out[z] = outs[z];
    }
    dim3 gg(divup(N, 64), 8);
    if (l == 0)      gemm4_reg<6, 4><<<gg, blk, 0, stream>>>(Ah, Al, ga, N, K, M);
    else if (l == 1) gemm4_reg<8, 4><<<gg, blk, 0, stream>>>(Ah, Al, ga, N, K, M);
    else             gemm4_reg<8, 3><<<gg, blk, 0, stream>>>(Ah, Al, ga, N, K, M);

    dim3 gat(divup(N * 64, 256));
    if (l < 2) {
      attn_fused<4, 16><<<gat, blk, 0, stream>>>(qb, kb, vb, We[l], startb, src_s,
                                                 ea_s, eid_s, sc, lay_out[l],
                                                 alpha_out[l], N, cfg[l].scale);
    } else {
      attn_fused<6, 8><<<gat, blk, 0, stream>>>(qb, kb, vb, We[l], startb, src_s,
                                                ea_s, eid_s, sc, lay_out[l],
                                                alpha_out[l], N, cfg[l].scale);
    }
    if (l == 0) ln_relu<<<divup(N, 4), blk, 0, stream>>>(xa, g1, be1, xa, N);
    if (l == 1) ln_relu<<<divup(N, 4), blk, 0, stream>>>(xb, g2, be2, xb, N);
  }

  fill_i32<<<divup(B * 192 + B, 256), blk, 0, stream>>>((int*)pooled, 0, B * 192 + B);
  resid_pool2<<<divup(N, 128), dim3(192), 0, stream>>>(x, xa, batch, pooled, cnt, N, 128);
  head_mlp<<<B, dim3(64), 0, stream>>>(pooled, cnt, fc1w, fc1b, fc2w, fc2b, logits);
}

// Round 7
// 835.538 us; speedup vs baseline: 1.4782x; 1.2813x over previous
//
#include <hip/hip_runtime.h>
#include <cstdint>
#include <cstddef>

#define DEVINL __device__ __forceinline__

typedef short s16x8 __attribute__((ext_vector_type(8)));   // 8 bf16 in 4 VGPRs
typedef float f32x4 __attribute__((ext_vector_type(4)));

DEVINL unsigned short f2bf(float f) {
  unsigned u = __float_as_uint(f);
  unsigned r = (u + 0x7FFFu + ((u >> 16) & 1u)) >> 16;
  return (unsigned short)r;
}
DEVINL float bf2f(unsigned short b) { return __uint_as_float(((unsigned)b) << 16); }

__global__ __launch_bounds__(256) void fill_i32(int* __restrict__ p, int val, int n) {
  int i = blockIdx.x * 256 + threadIdx.x;
  if (i < n) p[i] = val;
}

// ---------------- bf16 hi/lo split conversions ----------------

__global__ __launch_bounds__(256) void cvt_split(const float* __restrict__ in,
                                                 unsigned short* __restrict__ hi,
                                                 unsigned short* __restrict__ lo, int n) {
  int i = blockIdx.x * 256 + threadIdx.x;
  if (i >= n) return;
  float f = in[i];
  unsigned short h = f2bf(f);
  float r = f - bf2f(h);
  hi[i] = h;
  lo[i] = f2bf(r);
}

// W[K,M] fp32 -> Wt_hi/lo[M,K] bf16 (transposed for contiguous B fragments)
__global__ __launch_bounds__(256) void cvt_w(const float* __restrict__ W,
                                             unsigned short* __restrict__ Wh,
                                             unsigned short* __restrict__ Wl,
                                             int K, int M) {
  int i = blockIdx.x * 256 + threadIdx.x;
  if (i >= K * M) return;
  int k = i / M, m = i - k * M;
  float f = W[i];
  unsigned short h = f2bf(f);
  float r = f - bf2f(h);
  Wh[(size_t)m * K + k] = h;
  Wl[(size_t)m * K + k] = f2bf(r);
}

// ---------------- LDS-tiled fused 4-matrix MFMA GEMM (bf16x3) -------
// Tile: 128 rows x 64 cols, BK=64. grid: (mt*4 [z,colTile], rowTiles).
// R4/R5 lesson: LLVM will NOT keep a 64-VGPR A array live across a loop
// (VGPR_Count 52/60 with spill-reloads, MfmaUtil 6%) -> deterministic
// reuse via LDS instead.
struct GemmArgs {
  const unsigned short* Wh[4];
  const unsigned short* Wl[4];
  const float* bias[4];
  float* out[4];
};

template <int KTOT>   // 192 or 256
__global__ __launch_bounds__(256, 2) void gemm4_lds(
    const unsigned short* __restrict__ Ah, const unsigned short* __restrict__ Al,
    GemmArgs args, int N, int M) {
  const int BK = 64;
  const int LDK = 72;                 // +8 shorts pad: 16B-aligned, kills pow2 stride
  __shared__ unsigned short ash[128 * LDK];
  __shared__ unsigned short asl[128 * LDK];
  __shared__ unsigned short wsh[64 * LDK];
  __shared__ unsigned short wsl[64 * LDK];
  int tid = threadIdx.x;
  int wave = tid >> 6, lane = tid & 63;
  int lrow = lane & 15, quad = lane >> 4;
  int mt = M >> 6;
  int z = blockIdx.x / mt;
  int colTile = blockIdx.x - z * mt;
  int row0 = blockIdx.y * 128;
  int col0 = colTile * 64;
  const unsigned short* __restrict__ Wh = args.Wh[z];
  const unsigned short* __restrict__ Wl = args.Wl[z];

  f32x4 acc[2][4] = {};

  for (int k0 = 0; k0 < KTOT; k0 += BK) {
    __syncthreads();
    // stage A-tile: 128 rows x 64 k (hi+lo). 1024 16B-chunks, 4 per thread.
#pragma unroll
    for (int i = 0; i < 4; i++) {
      int c = tid + i * 256;
      int r = c >> 3, kq = c & 7;
      int gr = row0 + r; if (gr >= N) gr = N - 1;   // clamp; C-write guards rows
      size_t g = (size_t)gr * KTOT + k0 + kq * 8;
      *(s16x8*)(ash + r * LDK + kq * 8) = *(const s16x8*)(Ah + g);
      *(s16x8*)(asl + r * LDK + kq * 8) = *(const s16x8*)(Al + g);
    }
    // stage W-tile: 64 cols x 64 k (hi+lo). 512 chunks, 2 per thread.
#pragma unroll
    for (int i = 0; i < 2; i++) {
      int c = tid + i * 256;
      int r = c >> 3, kq = c & 7;
      size_t g = (size_t)(col0 + r) * KTOT + k0 + kq * 8;
      *(s16x8*)(wsh + r * LDK + kq * 8) = *(const s16x8*)(Wh + g);
      *(s16x8*)(wsl + r * LDK + kq * 8) = *(const s16x8*)(Wl + g);
    }
    __syncthreads();
#pragma unroll
    for (int kk = 0; kk < 2; kk++) {
      s16x8 fah[2], fal[2], fbh[4], fbl[4];
#pragma unroll
      for (int rf = 0; rf < 2; rf++) {
        int r = wave * 32 + rf * 16 + lrow;
        fah[rf] = *(const s16x8*)(ash + r * LDK + kk * 32 + quad * 8);
        fal[rf] = *(const s16x8*)(asl + r * LDK + kk * 32 + quad * 8);
      }
#pragma unroll
      for (int cf = 0; cf < 4; cf++) {
        int cc = cf * 16 + lrow;
        fbh[cf] = *(const s16x8*)(wsh + cc * LDK + kk * 32 + quad * 8);
        fbl[cf] = *(const s16x8*)(wsl + cc * LDK + kk * 32 + quad * 8);
      }
#pragma unroll
      for (int rf = 0; rf < 2; rf++)
#pragma unroll
        for (int cf = 0; cf < 4; cf++) {
          acc[rf][cf] = __builtin_amdgcn_mfma_f32_16x16x32_bf16(fah[rf], fbh[cf], acc[rf][cf], 0, 0, 0);
          acc[rf][cf] = __builtin_amdgcn_mfma_f32_16x16x32_bf16(fal[rf], fbh[cf], acc[rf][cf], 0, 0, 0);
          acc[rf][cf] = __builtin_amdgcn_mfma_f32_16x16x32_bf16(fah[rf], fbl[cf], acc[rf][cf], 0, 0, 0);
        }
    }
  }
  // epilogue: C/D layout col=lane&15, row=quad*4+reg
  const float* __restrict__ bias = args.bias[z];
  float* __restrict__ C = args.out[z];
#pragma unroll
  for (int cf = 0; cf < 4; cf++) {
    int col = col0 + cf * 16 + lrow;
    float bv = bias[col];
#pragma unroll
    for (int rf = 0; rf < 2; rf++) {
      int rb = row0 + wave * 32 + rf * 16 + quad * 4;
#pragma unroll
      for (int r = 0; r < 4; r++) {
        int rr = rb + r;
        if (rr < N) C[(size_t)rr * M + col] = acc[rf][cf][r] + bv;
      }
    }
  }
}

// ---------------- counting sort of edges by dst ----------------

__global__ __launch_bounds__(256) void hist_dst(const int* __restrict__ dst,
                                                int* __restrict__ cnt, int E) {
  int e = blockIdx.x * 256 + threadIdx.x;
  if (e < E) atomicAdd(&cnt[dst[e] + 1], 1);
}

__global__ __launch_bounds__(1024) void scan_hist(const int* __restrict__ cnt,
                                                  int* __restrict__ start,
                                                  int* __restrict__ off, int N) {
  __shared__ int sums[1024];
  const int CH = 20;
  int t = threadIdx.x;
  int base = t * CH;
  int local[CH];
  int tot = 0;
  if (base < N) {
#pragma unroll
    for (int i = 0; i < CH; i++) { local[i] = cnt[base + i]; tot += local[i]; }
  }
  sums[t] = tot;
  __syncthreads();
  for (int d = 1; d < 1024; d <<= 1) {
    int v = (t >= d) ? sums[t - d] : 0;
    __syncthreads();
    sums[t] += v;
    __syncthreads();
  }
  if (base < N) {
    int run = (t == 0) ? 0 : sums[t - 1];
#pragma unroll
    for (int i = 0; i < CH; i++) { start[base + i] = run; off[base + i] = run; run += local[i]; }
    if (base + CH == N) start[N] = run;
  }
}

__global__ __launch_bounds__(256) void scatter_edges(
    const int* __restrict__ src, const int* __restrict__ dst,
    const float* __restrict__ ea, int* __restrict__ off,
    int* __restrict__ src_s, float* __restrict__ ea_s, int* __restrict__ eid_s, int E) {
  int e = blockIdx.x * 256 + threadIdx.x;
  if (e >= E) return;
  int d = dst[e] + 1;
  int pos = atomicAdd(&off[d], 1);
  src_s[pos] = src[e] + 1;
  ea_s[pos] = ea[e];
  eid_s[pos] = e;
}

// ---------------- fused per-dst attention (flash-style) ----------------
template <int H, int LPH>
__global__ __launch_bounds__(256) void attn_fused(
    const float* __restrict__ q, const float* __restrict__ k,
    const float* __restrict__ v, const float* __restrict__ We,
    const int* __restrict__ start, const int* __restrict__ src_s,
    const float* __restrict__ ea_s, const int* __restrict__ eid_s,
    float* __restrict__ sc, float* __restrict__ outp,
    float* __restrict__ alpha, int Nn, float scale) {
  const int HC = H * LPH * 4;
  int w = (blockIdx.x * 256 + threadIdx.x) >> 6;
  int lane = threadIdx.x & 63;
  if (w >= Nn) return;
  int b = start[w], e = start[w + 1];
  if (b == e) return;
  bool act = lane < H * LPH;
  int idx = lane * 4;
  int head = lane / LPH;
  float4 q4 = make_float4(0.f, 0.f, 0.f, 0.f), We4 = q4;
  if (act) {
    q4 = *(const float4*)(q + (size_t)w * HC + idx);
    We4 = *(const float4*)(We + idx);
  }
  float m = -INFINITY, l = 0.f;
  float4 acc = make_float4(0.f, 0.f, 0.f, 0.f);
  for (int pos = b; pos < e; pos++) {
    int s = src_s[pos];
    float eav = ea_s[pos];
    float4 k4 = make_float4(0.f, 0.f, 0.f, 0.f);
    float4 v4 = k4;
    if (act) {
      k4 = *(const float4*)(k + (size_t)s * HC + idx);
      v4 = *(const float4*)(v + (size_t)s * HC + idx);
    }
    k4.x = fmaf(eav, We4.x, k4.x); k4.y = fmaf(eav, We4.y, k4.y);
    k4.z = fmaf(eav, We4.z, k4.z); k4.w = fmaf(eav, We4.w, k4.w);
    v4.x = fmaf(eav, We4.x, v4.x); v4.y = fmaf(eav, We4.y, v4.y);
    v4.z = fmaf(eav, We4.z, v4.z); v4.w = fmaf(eav, We4.w, v4.w);
    float p = q4.x * k4.x + q4.y * k4.y + q4.z * k4.z + q4.w * k4.w;
#pragma unroll
    for (int mm = 1; mm < LPH; mm <<= 1) p += __shfl_xor(p, mm, 64);
    float score = p * scale;
    if (act && (lane % LPH) == 0) sc[(size_t)pos * H + head] = score;
    float mn = fmaxf(m, score);
    float f = __expf(m - mn);
    float es = __expf(score - mn);
    l = l * f + es;
    m = mn;
    acc.x = fmaf(acc.x, f, es * v4.x);
    acc.y = fmaf(acc.y, f, es * v4.y);
    acc.z = fmaf(acc.z, f, es * v4.z);
    acc.w = fmaf(acc.w, f, es * v4.w);
  }
  float invl = 1.0f / (l + 1e-16f);
  if (act) {
    float* orow = outp + (size_t)w * HC + idx;
    float4 o = *(float4*)orow;
    o.x += acc.x * invl; o.y += acc.y * invl;
    o.z += acc.z * invl; o.w += acc.w * invl;
    *(float4*)orow = o;
  }
  for (int pos = b; pos < e; pos++) {
    if (act && (lane % LPH) == 0) {
      float sv = sc[(size_t)pos * H + head];
      alpha[(size_t)eid_s[pos] * H + head] = __expf(sv - m) * invl;
    }
  }
}

// ---------------- misc dense kernels ----------------

__global__ __launch_bounds__(256) void ln_relu(
    const float* __restrict__ in, const float* __restrict__ g,
    const float* __restrict__ b, float* __restrict__ o, int N) {
  int w = (blockIdx.x * 256 + threadIdx.x) >> 6;
  int lane = threadIdx.x & 63;
  if (w >= N) return;
  float4 x = *(const float4*)(in + (size_t)w * 256 + lane * 4);
  float s = x.x + x.y + x.z + x.w;
  float s2 = x.x * x.x + x.y * x.y + x.z * x.z + x.w * x.w;
  for (int m = 1; m < 64; m <<= 1) { s += __shfl_xor(s, m, 64); s2 += __shfl_xor(s2, m, 64); }
  float mu = s * (1.0f / 256.0f);
  float var = s2 * (1.0f / 256.0f) - mu * mu;
  float inv = rsqrtf(var + 1e-5f);
  float4 gv = *(const float4*)(g + lane * 4);
  float4 bv = *(const float4*)(b + lane * 4);
  float4 y;
  y.x = fmaxf(fmaf((x.x - mu) * inv, gv.x, bv.x), 0.f);
  y.y = fmaxf(fmaf((x.y - mu) * inv, gv.y, bv.y), 0.f);
  y.z = fmaxf(fmaf((x.z - mu) * inv, gv.z, bv.z), 0.f);
  y.w = fmaxf(fmaf((x.w - mu) * inv, gv.w, bv.w), 0.f);
  *(float4*)(o + (size_t)w * 256 + lane * 4) = y;
}

__global__ __launch_bounds__(192) void resid_pool2(
    const float* __restrict__ x, const float* __restrict__ x3,
    const int* __restrict__ batch, float* __restrict__ pooled,
    float* __restrict__ cnt, int N, int R) {
  int col = threadIdx.x;  // 0..191
  int r0 = blockIdx.x * R;
  int r1 = min(r0 + R, N);
  if (r0 >= N) return;
  float acc = 0.f;
  int cur = batch[r0];
  int run = 0;
  for (int r = r0; r < r1; r++) {
    int b = batch[r];
    if (b != cur) {
      atomicAdd(&pooled[cur * 192 + col], acc);
      if (col == 0) atomicAdd(&cnt[cur], (float)run);
      acc = 0.f; run = 0; cur = b;
    }
    size_t i = (size_t)r * 192 + col;
    acc += x[i] + fmaxf(x3[i], 0.f);
    run++;
  }
  atomicAdd(&pooled[cur * 192 + col], acc);
  if (col == 0) atomicAdd(&cnt[cur], (float)run);
}

__global__ __launch_bounds__(64) void head_mlp(
    const float* __restrict__ pooled, const float* __restrict__ cnt,
    const float* __restrict__ fc1w, const float* __restrict__ fc1b,
    const float* __restrict__ fc2w, const float* __restrict__ fc2b,
    float* __restrict__ logits) {
  int b = blockIdx.x;
  int t = threadIdx.x;
  __shared__ float p[192];
  __shared__ float hbuf[32];
  float inv = 1.0f / fmaxf(cnt[b], 1.0f);
  for (int i = t; i < 192; i += 64) p[i] = pooled[b * 192 + i] * inv;
  __syncthreads();
  if (t < 32) {
    float acc = fc1b[t];
    for (int i = 0; i < 192; i++) acc = fmaf(p[i], fc1w[i * 32 + t], acc);
    hbuf[t] = fmaxf(acc, 0.f);
  }
  __syncthreads();
  if (t < 2) {
    float acc = fc2b[t];
    for (int j = 0; j < 32; j++) acc = fmaf(hbuf[j], fc2w[j * 2 + t], acc);
    logits[b * 2 + t] = acc;
  }
}

static inline int divup(int a, int b) { return (a + b - 1) / b; }

extern "C" void kernel_launch(void* const* d_in, const int* in_sizes, int n_in,
                              void* d_out, int out_size, void* d_ws, size_t ws_size,
                              hipStream_t stream) {
  const int N = 20000, E = 320000, B = 64;
  const float* x     = (const float*)d_in[0];
  const int*   ei    = (const int*)d_in[1];
  const float* eattr = (const float*)d_in[2];
  const int*   batch = (const int*)d_in[3];
  const int* srcp = ei;
  const int* dstp = ei + E;

  const float* Wq[3]; const float* bq[3]; const float* Wk[3]; const float* bk[3];
  const float* Wv[3]; const float* bv[3]; const float* We[3]; const float* Ws[3];
  const float* bs[3];
  for (int l = 0; l < 3; l++) {
    int base = 4 + l * 9;
    Wq[l] = (const float*)d_in[base + 0]; bq[l] = (const float*)d_in[base + 1];
    Wk[l] = (const float*)d_in[base + 2]; bk[l] = (const float*)d_in[base + 3];
    Wv[l] = (const float*)d_in[base + 4]; bv[l] = (const float*)d_in[base + 5];
    We[l] = (const float*)d_in[base + 6];
    Ws[l] = (const float*)d_in[base + 7]; bs[l] = (const float*)d_in[base + 8];
  }
  const float* g1  = (const float*)d_in[31]; const float* be1 = (const float*)d_in[32];
  const float* g2  = (const float*)d_in[33]; const float* be2 = (const float*)d_in[34];
  const float* fc1w = (const float*)d_in[35]; const float* fc1b = (const float*)d_in[36];
  const float* fc2w = (const float*)d_in[37]; const float* fc2b = (const float*)d_in[38];

  float* out = (float*)d_out;
  float* logits = out;
  float* a1 = out + 128;
  float* a2 = a1 + (size_t)E * 4;
  float* a3 = a2 + (size_t)E * 4;

  float* ws = (float*)d_ws;
  size_t o = 0;
  float* qb = ws + o; o += (size_t)N * 256;
  float* kb = ws + o; o += (size_t)N * 256;
  float* vb = ws + o; o += (size_t)N * 256;
  float* xa = ws + o; o += (size_t)N * 256;
  float* xb = ws + o; o += (size_t)N * 256;
  float* sc = ws + o; o += (size_t)E * 6;
  int*   cntb  = (int*)(ws + o); o += N;
  int*   startb= (int*)(ws + o); o += N + 1;
  int*   offb  = (int*)(ws + o); o += N + 1;
  int*   src_s = (int*)(ws + o); o += E;
  float* ea_s  = ws + o; o += E;
  int*   eid_s = (int*)(ws + o); o += E;
  float* pooled = ws + o; o += (size_t)B * 192;
  float* cnt    = ws + o; o += B;
  unsigned short* Ah = (unsigned short*)(ws + o); o += (size_t)N * 128;
  unsigned short* Al = (unsigned short*)(ws + o); o += (size_t)N * 128;
  unsigned short* Wh12 = (unsigned short*)(ws + o); o += (size_t)12 * 32768;
  unsigned short* Wl12 = (unsigned short*)(ws + o); o += (size_t)12 * 32768;

  dim3 blk(256);

  struct LayerCfg { int K, M; float scale; };
  LayerCfg cfg[3] = {
    {192, 256, 0.125f},
    {256, 256, 0.125f},
    {256, 192, 0.1767766952966369f},
  };
  const float* Wmats[12];
  for (int l = 0; l < 3; l++) {
    Wmats[l * 4 + 0] = Wq[l]; Wmats[l * 4 + 1] = Wk[l];
    Wmats[l * 4 + 2] = Wv[l]; Wmats[l * 4 + 3] = Ws[l];
  }
  for (int i = 0; i < 12; i++) {
    int l = i / 4;
    int KM = cfg[l].K * cfg[l].M;
    cvt_w<<<divup(KM, 256), blk, 0, stream>>>(Wmats[i], Wh12 + (size_t)i * 65536,
                                              Wl12 + (size_t)i * 65536, cfg[l].K, cfg[l].M);
  }

  // ---- counting sort of edges by dst ----
  fill_i32<<<divup(N, 256), blk, 0, stream>>>(cntb, 0, N);
  hist_dst<<<divup(E, 256), blk, 0, stream>>>(dstp, cntb, E);
  scan_hist<<<1, dim3(1024), 0, stream>>>(cntb, startb, offb, N);
  scatter_edges<<<divup(E, 256), blk, 0, stream>>>(srcp, dstp, eattr, offb,
                                                  src_s, ea_s, eid_s, E);

  const float* lin_in[3]  = {x, xa, xb};
  float*       lay_out[3] = {xa, xb, xa};
  float*       alpha_out[3] = {a1, a2, a3};

  for (int l = 0; l < 3; l++) {
    int K = cfg[l].K, M = cfg[l].M;
    cvt_split<<<divup(N * K, 256), blk, 0, stream>>>(lin_in[l], Ah, Al, N * K);
    GemmArgs ga;
    float* outs[4] = {qb, kb, vb, lay_out[l]};
    const float* biases[4] = {bq[l], bk[l], bv[l], bs[l]};
    for (int z = 0; z < 4; z++) {
      ga.Wh[z] = Wh12 + (size_t)(l * 4 + z) * 65536;
      ga.Wl[z] = Wl12 + (size_t)(l * 4 + z) * 65536;
      ga.bias[z] = biases[z];
      ga.out[z] = outs[z];
    }
    dim3 gg((M >> 6) * 4, divup(N, 128));
    if (l == 0)      gemm4_lds<192><<<gg, blk, 0, stream>>>(Ah, Al, ga, N, M);
    else             gemm4_lds<256><<<gg, blk, 0, stream>>>(Ah, Al, ga, N, M);

    dim3 gat(divup(N * 64, 256));
    if (l < 2) {
      attn_fused<4, 16><<<gat, blk, 0, stream>>>(qb, kb, vb, We[l], startb, src_s,
                                                 ea_s, eid_s, sc, lay_out[l],
                                                 alpha_out[l], N, cfg[l].scale);
    } else {
      attn_fused<6, 8><<<gat, blk, 0, stream>>>(qb, kb, vb, We[l], startb, src_s,
                                                ea_s, eid_s, sc, lay_out[l],
                                                alpha_out[l], N, cfg[l].scale);
    }
    if (l == 0) ln_relu<<<divup(N, 4), blk, 0, stream>>>(xa, g1, be1, xa, N);
    if (l == 1) ln_relu<<<divup(N, 4), blk, 0, stream>>>(xb, g2, be2, xb, N);
  }

  fill_i32<<<divup(B * 192 + B, 256), blk, 0, stream>>>((int*)pooled, 0, B * 192 + B);
  resid_pool2<<<divup(N, 128), dim3(192), 0, stream>>>(x, xa, batch, pooled, cnt, N, 128);
  head_mlp<<<B, dim3(64), 0, stream>>>(pooled, cnt, fc1w, fc1b, fc2w, fc2b, logits);
}

// Round 8
// 796.885 us; speedup vs baseline: 1.5499x; 1.0485x over previous
//
#include <hip/hip_runtime.h>
#include <cstdint>
#include <cstddef>

#define DEVINL __device__ __forceinline__

typedef short s16x8 __attribute__((ext_vector_type(8)));   // 8 bf16 in 4 VGPRs
typedef float f32x4 __attribute__((ext_vector_type(4)));
typedef unsigned short u16x4 __attribute__((ext_vector_type(4)));

DEVINL unsigned short f2bf(float f) {
  unsigned u = __float_as_uint(f);
  unsigned r = (u + 0x7FFFu + ((u >> 16) & 1u)) >> 16;
  return (unsigned short)r;
}
DEVINL float bf2f(unsigned short b) { return __uint_as_float(((unsigned)b) << 16); }

__global__ __launch_bounds__(256) void fill_i32(int* __restrict__ p, int val, int n) {
  int i = blockIdx.x * 256 + threadIdx.x;
  if (i < n) p[i] = val;
}

// ---------------- bf16 hi/lo split conversions ----------------

__global__ __launch_bounds__(256) void cvt_split(const float* __restrict__ in,
                                                 unsigned short* __restrict__ hi,
                                                 unsigned short* __restrict__ lo, int n) {
  int i = blockIdx.x * 256 + threadIdx.x;
  if (i >= n) return;
  float f = in[i];
  unsigned short h = f2bf(f);
  float r = f - bf2f(h);
  hi[i] = h;
  lo[i] = f2bf(r);
}

// W[K,M] fp32 -> Wt_hi/lo[M,K] bf16 (transposed for contiguous B fragments)
__global__ __launch_bounds__(256) void cvt_w(const float* __restrict__ W,
                                             unsigned short* __restrict__ Wh,
                                             unsigned short* __restrict__ Wl,
                                             int K, int M) {
  int i = blockIdx.x * 256 + threadIdx.x;
  if (i >= K * M) return;
  int k = i / M, m = i - k * M;
  float f = W[i];
  unsigned short h = f2bf(f);
  float r = f - bf2f(h);
  Wh[(size_t)m * K + k] = h;
  Wl[(size_t)m * K + k] = f2bf(r);
}

// ---------------- LDS-tiled fused 4-matrix MFMA GEMM (bf16x3) -------
// Tile: 128 rows x 64 cols, BK=64. grid: (mt*4 [z,colTile], rowTiles).
// z=0..2 (q,k,v) write bf16 (attn gathers half the bytes); z=3 writes fp32.
struct GemmArgs {
  const unsigned short* Wh[4];
  const unsigned short* Wl[4];
  const float* bias[4];
  float* out[4];
  int obf[4];        // 1 -> out is bf16 (ushort), 0 -> fp32
};

template <int KTOT>   // 192 or 256
__global__ __launch_bounds__(256, 2) void gemm4_lds(
    const unsigned short* __restrict__ Ah, const unsigned short* __restrict__ Al,
    GemmArgs args, int N, int M) {
  const int BK = 64;
  const int LDK = 72;                 // +8 shorts pad: 16B-aligned, kills pow2 stride
  __shared__ unsigned short ash[128 * LDK];
  __shared__ unsigned short asl[128 * LDK];
  __shared__ unsigned short wsh[64 * LDK];
  __shared__ unsigned short wsl[64 * LDK];
  int tid = threadIdx.x;
  int wave = tid >> 6, lane = tid & 63;
  int lrow = lane & 15, quad = lane >> 4;
  int mt = M >> 6;
  int z = blockIdx.x / mt;
  int colTile = blockIdx.x - z * mt;
  int row0 = blockIdx.y * 128;
  int col0 = colTile * 64;
  const unsigned short* __restrict__ Wh = args.Wh[z];
  const unsigned short* __restrict__ Wl = args.Wl[z];

  f32x4 acc[2][4] = {};

  for (int k0 = 0; k0 < KTOT; k0 += BK) {
    __syncthreads();
#pragma unroll
    for (int i = 0; i < 4; i++) {
      int c = tid + i * 256;
      int r = c >> 3, kq = c & 7;
      int gr = row0 + r; if (gr >= N) gr = N - 1;   // clamp; C-write guards rows
      size_t g = (size_t)gr * KTOT + k0 + kq * 8;
      *(s16x8*)(ash + r * LDK + kq * 8) = *(const s16x8*)(Ah + g);
      *(s16x8*)(asl + r * LDK + kq * 8) = *(const s16x8*)(Al + g);
    }
#pragma unroll
    for (int i = 0; i < 2; i++) {
      int c = tid + i * 256;
      int r = c >> 3, kq = c & 7;
      size_t g = (size_t)(col0 + r) * KTOT + k0 + kq * 8;
      *(s16x8*)(wsh + r * LDK + kq * 8) = *(const s16x8*)(Wh + g);
      *(s16x8*)(wsl + r * LDK + kq * 8) = *(const s16x8*)(Wl + g);
    }
    __syncthreads();
#pragma unroll
    for (int kk = 0; kk < 2; kk++) {
      s16x8 fah[2], fal[2], fbh[4], fbl[4];
#pragma unroll
      for (int rf = 0; rf < 2; rf++) {
        int r = wave * 32 + rf * 16 + lrow;
        fah[rf] = *(const s16x8*)(ash + r * LDK + kk * 32 + quad * 8);
        fal[rf] = *(const s16x8*)(asl + r * LDK + kk * 32 + quad * 8);
      }
#pragma unroll
      for (int cf = 0; cf < 4; cf++) {
        int cc = cf * 16 + lrow;
        fbh[cf] = *(const s16x8*)(wsh + cc * LDK + kk * 32 + quad * 8);
        fbl[cf] = *(const s16x8*)(wsl + cc * LDK + kk * 32 + quad * 8);
      }
#pragma unroll
      for (int rf = 0; rf < 2; rf++)
#pragma unroll
        for (int cf = 0; cf < 4; cf++) {
          acc[rf][cf] = __builtin_amdgcn_mfma_f32_16x16x32_bf16(fah[rf], fbh[cf], acc[rf][cf], 0, 0, 0);
          acc[rf][cf] = __builtin_amdgcn_mfma_f32_16x16x32_bf16(fal[rf], fbh[cf], acc[rf][cf], 0, 0, 0);
          acc[rf][cf] = __builtin_amdgcn_mfma_f32_16x16x32_bf16(fah[rf], fbl[cf], acc[rf][cf], 0, 0, 0);
        }
    }
  }
  // epilogue: C/D layout col=lane&15, row=quad*4+reg
  const float* __restrict__ bias = args.bias[z];
  int obf = args.obf[z];
  if (obf) {
    unsigned short* __restrict__ C = (unsigned short*)args.out[z];
#pragma unroll
    for (int cf = 0; cf < 4; cf++) {
      int col = col0 + cf * 16 + lrow;
      float bv = bias[col];
#pragma unroll
      for (int rf = 0; rf < 2; rf++) {
        int rb = row0 + wave * 32 + rf * 16 + quad * 4;
#pragma unroll
        for (int r = 0; r < 4; r++) {
          int rr = rb + r;
          if (rr < N) C[(size_t)rr * M + col] = f2bf(acc[rf][cf][r] + bv);
        }
      }
    }
  } else {
    float* __restrict__ C = args.out[z];
#pragma unroll
    for (int cf = 0; cf < 4; cf++) {
      int col = col0 + cf * 16 + lrow;
      float bv = bias[col];
#pragma unroll
      for (int rf = 0; rf < 2; rf++) {
        int rb = row0 + wave * 32 + rf * 16 + quad * 4;
#pragma unroll
        for (int r = 0; r < 4; r++) {
          int rr = rb + r;
          if (rr < N) C[(size_t)rr * M + col] = acc[rf][cf][r] + bv;
        }
      }
    }
  }
}

// ---------------- counting sort of edges by dst ----------------

__global__ __launch_bounds__(256) void hist_dst(const int* __restrict__ dst,
                                                int* __restrict__ cnt, int E) {
  int e = blockIdx.x * 256 + threadIdx.x;
  if (e < E) atomicAdd(&cnt[dst[e] + 1], 1);
}

__global__ __launch_bounds__(1024) void scan_hist(const int* __restrict__ cnt,
                                                  int* __restrict__ start,
                                                  int* __restrict__ off, int N) {
  __shared__ int sums[1024];
  const int CH = 20;
  int t = threadIdx.x;
  int base = t * CH;
  int local[CH];
  int tot = 0;
  if (base < N) {
#pragma unroll
    for (int i = 0; i < CH; i++) { local[i] = cnt[base + i]; tot += local[i]; }
  }
  sums[t] = tot;
  __syncthreads();
  for (int d = 1; d < 1024; d <<= 1) {
    int v = (t >= d) ? sums[t - d] : 0;
    __syncthreads();
    sums[t] += v;
    __syncthreads();
  }
  if (base < N) {
    int run = (t == 0) ? 0 : sums[t - 1];
#pragma unroll
    for (int i = 0; i < CH; i++) { start[base + i] = run; off[base + i] = run; run += local[i]; }
    if (base + CH == N) start[N] = run;
  }
}

__global__ __launch_bounds__(256) void scatter_edges(
    const int* __restrict__ src, const int* __restrict__ dst,
    const float* __restrict__ ea, int* __restrict__ off,
    int* __restrict__ src_s, float* __restrict__ ea_s, int* __restrict__ eid_s, int E) {
  int e = blockIdx.x * 256 + threadIdx.x;
  if (e >= E) return;
  int d = dst[e] + 1;
  int pos = atomicAdd(&off[d], 1);
  src_s[pos] = src[e] + 1;
  ea_s[pos] = ea[e];
  eid_s[pos] = e;
}

// ---------------- fused per-dst attention (flash-style, bf16 q/k/v) -------
template <int H, int LPH>
__global__ __launch_bounds__(256) void attn_fused(
    const unsigned short* __restrict__ q, const unsigned short* __restrict__ k,
    const unsigned short* __restrict__ v, const float* __restrict__ We,
    const int* __restrict__ start, const int* __restrict__ src_s,
    const float* __restrict__ ea_s, const int* __restrict__ eid_s,
    float* __restrict__ sc, float* __restrict__ outp,
    float* __restrict__ alpha, int Nn, float scale) {
  const int HC = H * LPH * 4;
  int w = (blockIdx.x * 256 + threadIdx.x) >> 6;
  int lane = threadIdx.x & 63;
  if (w >= Nn) return;
  int b = start[w], e = start[w + 1];
  if (b == e) return;
  bool act = lane < H * LPH;
  int idx = lane * 4;
  int head = lane / LPH;
  float4 q4 = make_float4(0.f, 0.f, 0.f, 0.f), We4 = q4;
  if (act) {
    u16x4 qv = *(const u16x4*)(q + (size_t)w * HC + idx);
    q4.x = bf2f(qv.x); q4.y = bf2f(qv.y); q4.z = bf2f(qv.z); q4.w = bf2f(qv.w);
    We4 = *(const float4*)(We + idx);
  }
  float m = -INFINITY, l = 0.f;
  float4 acc = make_float4(0.f, 0.f, 0.f, 0.f);
  for (int pos = b; pos < e; pos++) {
    int s = src_s[pos];
    float eav = ea_s[pos];
    float4 k4 = make_float4(0.f, 0.f, 0.f, 0.f);
    float4 v4 = k4;
    if (act) {
      u16x4 kv = *(const u16x4*)(k + (size_t)s * HC + idx);
      u16x4 vv = *(const u16x4*)(v + (size_t)s * HC + idx);
      k4.x = bf2f(kv.x); k4.y = bf2f(kv.y); k4.z = bf2f(kv.z); k4.w = bf2f(kv.w);
      v4.x = bf2f(vv.x); v4.y = bf2f(vv.y); v4.z = bf2f(vv.z); v4.w = bf2f(vv.w);
    }
    k4.x = fmaf(eav, We4.x, k4.x); k4.y = fmaf(eav, We4.y, k4.y);
    k4.z = fmaf(eav, We4.z, k4.z); k4.w = fmaf(eav, We4.w, k4.w);
    v4.x = fmaf(eav, We4.x, v4.x); v4.y = fmaf(eav, We4.y, v4.y);
    v4.z = fmaf(eav, We4.z, v4.z); v4.w = fmaf(eav, We4.w, v4.w);
    float p = q4.x * k4.x + q4.y * k4.y + q4.z * k4.z + q4.w * k4.w;
#pragma unroll
    for (int mm = 1; mm < LPH; mm <<= 1) p += __shfl_xor(p, mm, 64);
    float score = p * scale;
    if (act && (lane % LPH) == 0) sc[(size_t)pos * H + head] = score;
    float mn = fmaxf(m, score);
    float f = __expf(m - mn);
    float es = __expf(score - mn);
    l = l * f + es;
    m = mn;
    acc.x = fmaf(acc.x, f, es * v4.x);
    acc.y = fmaf(acc.y, f, es * v4.y);
    acc.z = fmaf(acc.z, f, es * v4.z);
    acc.w = fmaf(acc.w, f, es * v4.w);
  }
  float invl = 1.0f / (l + 1e-16f);
  if (act) {
    float* orow = outp + (size_t)w * HC + idx;
    float4 o = *(float4*)orow;
    o.x += acc.x * invl; o.y += acc.y * invl;
    o.z += acc.z * invl; o.w += acc.w * invl;
    *(float4*)orow = o;
  }
  for (int pos = b; pos < e; pos++) {
    if (act && (lane % LPH) == 0) {
      float sv = sc[(size_t)pos * H + head];
      alpha[(size_t)eid_s[pos] * H + head] = __expf(sv - m) * invl;
    }
  }
}

// ---------------- misc dense kernels ----------------

__global__ __launch_bounds__(256) void ln_relu(
    const float* __restrict__ in, const float* __restrict__ g,
    const float* __restrict__ b, float* __restrict__ o, int N) {
  int w = (blockIdx.x * 256 + threadIdx.x) >> 6;
  int lane = threadIdx.x & 63;
  if (w >= N) return;
  float4 x = *(const float4*)(in + (size_t)w * 256 + lane * 4);
  float s = x.x + x.y + x.z + x.w;
  float s2 = x.x * x.x + x.y * x.y + x.z * x.z + x.w * x.w;
  for (int m = 1; m < 64; m <<= 1) { s += __shfl_xor(s, m, 64); s2 += __shfl_xor(s2, m, 64); }
  float mu = s * (1.0f / 256.0f);
  float var = s2 * (1.0f / 256.0f) - mu * mu;
  float inv = rsqrtf(var + 1e-5f);
  float4 gv = *(const float4*)(g + lane * 4);
  float4 bv = *(const float4*)(b + lane * 4);
  float4 y;
  y.x = fmaxf(fmaf((x.x - mu) * inv, gv.x, bv.x), 0.f);
  y.y = fmaxf(fmaf((x.y - mu) * inv, gv.y, bv.y), 0.f);
  y.z = fmaxf(fmaf((x.z - mu) * inv, gv.z, bv.z), 0.f);
  y.w = fmaxf(fmaf((x.w - mu) * inv, gv.w, bv.w), 0.f);
  *(float4*)(o + (size_t)w * 256 + lane * 4) = y;
}

__global__ __launch_bounds__(192) void resid_pool2(
    const float* __restrict__ x, const float* __restrict__ x3,
    const int* __restrict__ batch, float* __restrict__ pooled,
    float* __restrict__ cnt, int N, int R) {
  int col = threadIdx.x;  // 0..191
  int r0 = blockIdx.x * R;
  int r1 = min(r0 + R, N);
  if (r0 >= N) return;
  float acc = 0.f;
  int cur = batch[r0];
  int run = 0;
  for (int r = r0; r < r1; r++) {
    int b = batch[r];
    if (b != cur) {
      atomicAdd(&pooled[cur * 192 + col], acc);
      if (col == 0) atomicAdd(&cnt[cur], (float)run);
      acc = 0.f; run = 0; cur = b;
    }
    size_t i = (size_t)r * 192 + col;
    acc += x[i] + fmaxf(x3[i], 0.f);
    run++;
  }
  atomicAdd(&pooled[cur * 192 + col], acc);
  if (col == 0) atomicAdd(&cnt[cur], (float)run);
}

__global__ __launch_bounds__(64) void head_mlp(
    const float* __restrict__ pooled, const float* __restrict__ cnt,
    const float* __restrict__ fc1w, const float* __restrict__ fc1b,
    const float* __restrict__ fc2w, const float* __restrict__ fc2b,
    float* __restrict__ logits) {
  int b = blockIdx.x;
  int t = threadIdx.x;
  __shared__ float p[192];
  __shared__ float hbuf[32];
  float inv = 1.0f / fmaxf(cnt[b], 1.0f);
  for (int i = t; i < 192; i += 64) p[i] = pooled[b * 192 + i] * inv;
  __syncthreads();
  if (t < 32) {
    float acc = fc1b[t];
    for (int i = 0; i < 192; i++) acc = fmaf(p[i], fc1w[i * 32 + t], acc);
    hbuf[t] = fmaxf(acc, 0.f);
  }
  __syncthreads();
  if (t < 2) {
    float acc = fc2b[t];
    for (int j = 0; j < 32; j++) acc = fmaf(hbuf[j], fc2w[j * 2 + t], acc);
    logits[b * 2 + t] = acc;
  }
}

static inline int divup(int a, int b) { return (a + b - 1) / b; }

extern "C" void kernel_launch(void* const* d_in, const int* in_sizes, int n_in,
                              void* d_out, int out_size, void* d_ws, size_t ws_size,
                              hipStream_t stream) {
  const int N = 20000, E = 320000, B = 64;
  const float* x     = (const float*)d_in[0];
  const int*   ei    = (const int*)d_in[1];
  const float* eattr = (const float*)d_in[2];
  const int*   batch = (const int*)d_in[3];
  const int* srcp = ei;
  const int* dstp = ei + E;

  const float* Wq[3]; const float* bq[3]; const float* Wk[3]; const float* bk[3];
  const float* Wv[3]; const float* bv[3]; const float* We[3]; const float* Ws[3];
  const float* bs[3];
  for (int l = 0; l < 3; l++) {
    int base = 4 + l * 9;
    Wq[l] = (const float*)d_in[base + 0]; bq[l] = (const float*)d_in[base + 1];
    Wk[l] = (const float*)d_in[base + 2]; bk[l] = (const float*)d_in[base + 3];
    Wv[l] = (const float*)d_in[base + 4]; bv[l] = (const float*)d_in[base + 5];
    We[l] = (const float*)d_in[base + 6];
    Ws[l] = (const float*)d_in[base + 7]; bs[l] = (const float*)d_in[base + 8];
  }
  const float* g1  = (const float*)d_in[31]; const float* be1 = (const float*)d_in[32];
  const float* g2  = (const float*)d_in[33]; const float* be2 = (const float*)d_in[34];
  const float* fc1w = (const float*)d_in[35]; const float* fc1b = (const float*)d_in[36];
  const float* fc2w = (const float*)d_in[37]; const float* fc2b = (const float*)d_in[38];

  float* out = (float*)d_out;
  float* logits = out;
  float* a1 = out + 128;
  float* a2 = a1 + (size_t)E * 4;
  float* a3 = a2 + (size_t)E * 4;

  float* ws = (float*)d_ws;
  size_t o = 0;
  float* qb = ws + o; o += (size_t)N * 256;   // holds bf16 q (ushort) now
  float* kb = ws + o; o += (size_t)N * 256;   // holds bf16 k
  float* vb = ws + o; o += (size_t)N * 256;   // holds bf16 v
  float* xa = ws + o; o += (size_t)N * 256;
  float* xb = ws + o; o += (size_t)N * 256;
  float* sc = ws + o; o += (size_t)E * 6;
  int*   cntb  = (int*)(ws + o); o += N;
  int*   startb= (int*)(ws + o); o += N + 1;
  int*   offb  = (int*)(ws + o); o += N + 1;
  int*   src_s = (int*)(ws + o); o += E;
  float* ea_s  = ws + o; o += E;
  int*   eid_s = (int*)(ws + o); o += E;
  float* pooled = ws + o; o += (size_t)B * 192;
  float* cnt    = ws + o; o += B;
  unsigned short* Ah = (unsigned short*)(ws + o); o += (size_t)N * 128;
  unsigned short* Al = (unsigned short*)(ws + o); o += (size_t)N * 128;
  unsigned short* Wh12 = (unsigned short*)(ws + o); o += (size_t)12 * 32768;
  unsigned short* Wl12 = (unsigned short*)(ws + o); o += (size_t)12 * 32768;

  unsigned short* qh = (unsigned short*)qb;
  unsigned short* kh = (unsigned short*)kb;
  unsigned short* vh = (unsigned short*)vb;

  dim3 blk(256);

  struct LayerCfg { int K, M; float scale; };
  LayerCfg cfg[3] = {
    {192, 256, 0.125f},
    {256, 256, 0.125f},
    {256, 192, 0.1767766952966369f},
  };
  const float* Wmats[12];
  for (int l = 0; l < 3; l++) {
    Wmats[l * 4 + 0] = Wq[l]; Wmats[l * 4 + 1] = Wk[l];
    Wmats[l * 4 + 2] = Wv[l]; Wmats[l * 4 + 3] = Ws[l];
  }
  for (int i = 0; i < 12; i++) {
    int l = i / 4;
    int KM = cfg[l].K * cfg[l].M;
    cvt_w<<<divup(KM, 256), blk, 0, stream>>>(Wmats[i], Wh12 + (size_t)i * 65536,
                                              Wl12 + (size_t)i * 65536, cfg[l].K, cfg[l].M);
  }

  // ---- counting sort of edges by dst ----
  fill_i32<<<divup(N, 256), blk, 0, stream>>>(cntb, 0, N);
  hist_dst<<<divup(E, 256), blk, 0, stream>>>(dstp, cntb, E);
  scan_hist<<<1, dim3(1024), 0, stream>>>(cntb, startb, offb, N);
  scatter_edges<<<divup(E, 256), blk, 0, stream>>>(srcp, dstp, eattr, offb,
                                                  src_s, ea_s, eid_s, E);

  const float* lin_in[3]  = {x, xa, xb};
  float*       lay_out[3] = {xa, xb, xa};
  float*       alpha_out[3] = {a1, a2, a3};

  for (int l = 0; l < 3; l++) {
    int K = cfg[l].K, M = cfg[l].M;
    cvt_split<<<divup(N * K, 256), blk, 0, stream>>>(lin_in[l], Ah, Al, N * K);
    GemmArgs ga;
    float* outs[4] = {(float*)qh, (float*)kh, (float*)vh, lay_out[l]};
    const float* biases[4] = {bq[l], bk[l], bv[l], bs[l]};
    for (int z = 0; z < 4; z++) {
      ga.Wh[z] = Wh12 + (size_t)(l * 4 + z) * 65536;
      ga.Wl[z] = Wl12 + (size_t)(l * 4 + z) * 65536;
      ga.bias[z] = biases[z];
      ga.out[z] = outs[z];
      ga.obf[z] = (z < 3) ? 1 : 0;
    }
    dim3 gg((M >> 6) * 4, divup(N, 128));
    if (l == 0)      gemm4_lds<192><<<gg, blk, 0, stream>>>(Ah, Al, ga, N, M);
    else             gemm4_lds<256><<<gg, blk, 0, stream>>>(Ah, Al, ga, N, M);

    dim3 gat(divup(N * 64, 256));
    if (l < 2) {
      attn_fused<4, 16><<<gat, blk, 0, stream>>>(qh, kh, vh, We[l], startb, src_s,
                                                 ea_s, eid_s, sc, lay_out[l],
                                                 alpha_out[l], N, cfg[l].scale);
    } else {
      attn_fused<6, 8><<<gat, blk, 0, stream>>>(qh, kh, vh, We[l], startb, src_s,
                                                ea_s, eid_s, sc, lay_out[l],
                                                alpha_out[l], N, cfg[l].scale);
    }
    if (l == 0) ln_relu<<<divup(N, 4), blk, 0, stream>>>(xa, g1, be1, xa, N);
    if (l == 1) ln_relu<<<divup(N, 4), blk, 0, stream>>>(xb, g2, be2, xb, N);
  }

  fill_i32<<<divup(B * 192 + B, 256), blk, 0, stream>>>((int*)pooled, 0, B * 192 + B);
  resid_pool2<<<divup(N, 128), dim3(192), 0, stream>>>(x, xa, batch, pooled, cnt, N, 128);
  head_mlp<<<B, dim3(64), 0, stream>>>(pooled, cnt, fc1w, fc1b, fc2w, fc2b, logits);
}

// Round 9
// 701.145 us; speedup vs baseline: 1.7616x; 1.1365x over previous
//
#include <hip/hip_runtime.h>
#include <cstdint>
#include <cstddef>

#define DEVINL __device__ __forceinline__

typedef short s16x8 __attribute__((ext_vector_type(8)));   // 8 bf16 in 4 VGPRs
typedef float f32x4 __attribute__((ext_vector_type(4)));
typedef unsigned short u16x4 __attribute__((ext_vector_type(4)));

DEVINL unsigned short f2bf(float f) {
  unsigned u = __float_as_uint(f);
  unsigned r = (u + 0x7FFFu + ((u >> 16) & 1u)) >> 16;
  return (unsigned short)r;
}
DEVINL float bf2f(unsigned short b) { return __uint_as_float(((unsigned)b) << 16); }

__global__ __launch_bounds__(256) void fill_i32(int* __restrict__ p, int val, int n) {
  int i = blockIdx.x * 256 + threadIdx.x;
  if (i < n) p[i] = val;
}

// ---------------- bf16 hi/lo split conversions ----------------

__global__ __launch_bounds__(256) void cvt_split(const float* __restrict__ in,
                                                 unsigned short* __restrict__ hi,
                                                 unsigned short* __restrict__ lo, int n) {
  int i = blockIdx.x * 256 + threadIdx.x;
  if (i >= n) return;
  float f = in[i];
  unsigned short h = f2bf(f);
  float r = f - bf2f(h);
  hi[i] = h;
  lo[i] = f2bf(r);
}

// all 12 weight matrices in one launch: W[K,M] fp32 -> Wt hi/lo [M,K] bf16
struct CvtWArgs {
  const float* W[12];
  int K[12];
  int M[12];
};
__global__ __launch_bounds__(256) void cvt_w_all(CvtWArgs a,
                                                 unsigned short* __restrict__ Wh,
                                                 unsigned short* __restrict__ Wl) {
  int tid = blockIdx.x * 256 + threadIdx.x;
  int mat = tid >> 16;
  int off = tid & 65535;
  if (mat >= 12) return;
  int K = a.K[mat], M = a.M[mat];
  if (off >= K * M) return;
  int k = off / M, m = off - k * M;
  float f = a.W[mat][off];
  unsigned short h = f2bf(f);
  float r = f - bf2f(h);
  size_t dst = (size_t)mat * 65536 + (size_t)m * K + k;
  Wh[dst] = h;
  Wl[dst] = f2bf(r);
}

// ---------------- LDS-tiled fused 4-matrix MFMA GEMM (bf16x3) -------
// Tile: 128 rows x 64 cols, BK=64. grid: (mt*4 [z,colTile], rowTiles).
// z=0..2 (q,k,v) write bf16 (attn gathers half the bytes); z=3 writes fp32.
struct GemmArgs {
  const unsigned short* Wh[4];
  const unsigned short* Wl[4];
  const float* bias[4];
  float* out[4];
  int obf[4];        // 1 -> out is bf16 (ushort), 0 -> fp32
};

template <int KTOT>   // 192 or 256
__global__ __launch_bounds__(256, 2) void gemm4_lds(
    const unsigned short* __restrict__ Ah, const unsigned short* __restrict__ Al,
    GemmArgs args, int N, int M) {
  const int BK = 64;
  const int LDK = 72;                 // +8 shorts pad: 16B-aligned, kills pow2 stride
  __shared__ unsigned short ash[128 * LDK];
  __shared__ unsigned short asl[128 * LDK];
  __shared__ unsigned short wsh[64 * LDK];
  __shared__ unsigned short wsl[64 * LDK];
  int tid = threadIdx.x;
  int wave = tid >> 6, lane = tid & 63;
  int lrow = lane & 15, quad = lane >> 4;
  int mt = M >> 6;
  int z = blockIdx.x / mt;
  int colTile = blockIdx.x - z * mt;
  int row0 = blockIdx.y * 128;
  int col0 = colTile * 64;
  const unsigned short* __restrict__ Wh = args.Wh[z];
  const unsigned short* __restrict__ Wl = args.Wl[z];

  f32x4 acc[2][4] = {};

  for (int k0 = 0; k0 < KTOT; k0 += BK) {
    __syncthreads();
#pragma unroll
    for (int i = 0; i < 4; i++) {
      int c = tid + i * 256;
      int r = c >> 3, kq = c & 7;
      int gr = row0 + r; if (gr >= N) gr = N - 1;   // clamp; C-write guards rows
      size_t g = (size_t)gr * KTOT + k0 + kq * 8;
      *(s16x8*)(ash + r * LDK + kq * 8) = *(const s16x8*)(Ah + g);
      *(s16x8*)(asl + r * LDK + kq * 8) = *(const s16x8*)(Al + g);
    }
#pragma unroll
    for (int i = 0; i < 2; i++) {
      int c = tid + i * 256;
      int r = c >> 3, kq = c & 7;
      size_t g = (size_t)(col0 + r) * KTOT + k0 + kq * 8;
      *(s16x8*)(wsh + r * LDK + kq * 8) = *(const s16x8*)(Wh + g);
      *(s16x8*)(wsl + r * LDK + kq * 8) = *(const s16x8*)(Wl + g);
    }
    __syncthreads();
#pragma unroll
    for (int kk = 0; kk < 2; kk++) {
      s16x8 fah[2], fal[2], fbh[4], fbl[4];
#pragma unroll
      for (int rf = 0; rf < 2; rf++) {
        int r = wave * 32 + rf * 16 + lrow;
        fah[rf] = *(const s16x8*)(ash + r * LDK + kk * 32 + quad * 8);
        fal[rf] = *(const s16x8*)(asl + r * LDK + kk * 32 + quad * 8);
      }
#pragma unroll
      for (int cf = 0; cf < 4; cf++) {
        int cc = cf * 16 + lrow;
        fbh[cf] = *(const s16x8*)(wsh + cc * LDK + kk * 32 + quad * 8);
        fbl[cf] = *(const s16x8*)(wsl + cc * LDK + kk * 32 + quad * 8);
      }
#pragma unroll
      for (int rf = 0; rf < 2; rf++)
#pragma unroll
        for (int cf = 0; cf < 4; cf++) {
          acc[rf][cf] = __builtin_amdgcn_mfma_f32_16x16x32_bf16(fah[rf], fbh[cf], acc[rf][cf], 0, 0, 0);
          acc[rf][cf] = __builtin_amdgcn_mfma_f32_16x16x32_bf16(fal[rf], fbh[cf], acc[rf][cf], 0, 0, 0);
          acc[rf][cf] = __builtin_amdgcn_mfma_f32_16x16x32_bf16(fah[rf], fbl[cf], acc[rf][cf], 0, 0, 0);
        }
    }
  }
  // epilogue: C/D layout col=lane&15, row=quad*4+reg
  const float* __restrict__ bias = args.bias[z];
  int obf = args.obf[z];
  if (obf) {
    unsigned short* __restrict__ C = (unsigned short*)args.out[z];
#pragma unroll
    for (int cf = 0; cf < 4; cf++) {
      int col = col0 + cf * 16 + lrow;
      float bv = bias[col];
#pragma unroll
      for (int rf = 0; rf < 2; rf++) {
        int rb = row0 + wave * 32 + rf * 16 + quad * 4;
#pragma unroll
        for (int r = 0; r < 4; r++) {
          int rr = rb + r;
          if (rr < N) C[(size_t)rr * M + col] = f2bf(acc[rf][cf][r] + bv);
        }
      }
    }
  } else {
    float* __restrict__ C = args.out[z];
#pragma unroll
    for (int cf = 0; cf < 4; cf++) {
      int col = col0 + cf * 16 + lrow;
      float bv = bias[col];
#pragma unroll
      for (int rf = 0; rf < 2; rf++) {
        int rb = row0 + wave * 32 + rf * 16 + quad * 4;
#pragma unroll
        for (int r = 0; r < 4; r++) {
          int rr = rb + r;
          if (rr < N) C[(size_t)rr * M + col] = acc[rf][cf][r] + bv;
        }
      }
    }
  }
}

// ---------------- counting sort of edges by dst ----------------

__global__ __launch_bounds__(256) void hist_dst(const int* __restrict__ dst,
                                                int* __restrict__ cnt, int E) {
  int e = blockIdx.x * 256 + threadIdx.x;
  if (e < E) atomicAdd(&cnt[dst[e] + 1], 1);
}

__global__ __launch_bounds__(1024) void scan_hist(const int* __restrict__ cnt,
                                                  int* __restrict__ start,
                                                  int* __restrict__ off, int N) {
  __shared__ int sums[1024];
  const int CH = 20;
  int t = threadIdx.x;
  int base = t * CH;
  int local[CH];
  int tot = 0;
  if (base < N) {
#pragma unroll
    for (int i = 0; i < CH; i++) { local[i] = cnt[base + i]; tot += local[i]; }
  }
  sums[t] = tot;
  __syncthreads();
  for (int d = 1; d < 1024; d <<= 1) {
    int v = (t >= d) ? sums[t - d] : 0;
    __syncthreads();
    sums[t] += v;
    __syncthreads();
  }
  if (base < N) {
    int run = (t == 0) ? 0 : sums[t - 1];
#pragma unroll
    for (int i = 0; i < CH; i++) { start[base + i] = run; off[base + i] = run; run += local[i]; }
    if (base + CH == N) start[N] = run;
  }
}

__global__ __launch_bounds__(256) void scatter_edges(
    const int* __restrict__ src, const int* __restrict__ dst,
    const float* __restrict__ ea, int* __restrict__ off,
    int* __restrict__ src_s, float* __restrict__ ea_s, int* __restrict__ eid_s, int E) {
  int e = blockIdx.x * 256 + threadIdx.x;
  if (e >= E) return;
  int d = dst[e] + 1;
  int pos = atomicAdd(&off[d], 1);
  src_s[pos] = src[e] + 1;
  ea_s[pos] = ea[e];
  eid_s[pos] = e;
}

// ------- fused per-dst attention (flash-style, bf16 q/k/v, SW-pipelined) ----
// R7 post-mortem: serial per-edge gather chain was the bottleneck (FETCH
// halved, dur -15% only). Depth-2 prefetch + 2x unroll overlaps the k/v
// gathers of edge pos+2/pos+3 with the compute of pos/pos+1.
template <int H, int LPH>
__global__ __launch_bounds__(256) void attn_fused(
    const unsigned short* __restrict__ q, const unsigned short* __restrict__ k,
    const unsigned short* __restrict__ v, const float* __restrict__ We,
    const int* __restrict__ start, const int* __restrict__ src_s,
    const float* __restrict__ ea_s, const int* __restrict__ eid_s,
    float* __restrict__ sc, float* __restrict__ outp,
    float* __restrict__ alpha, int Nn, float scale) {
  const int HC = H * LPH * 4;
  int w = (blockIdx.x * 256 + threadIdx.x) >> 6;
  int lane = threadIdx.x & 63;
  if (w >= Nn) return;
  int b = start[w], e = start[w + 1];
  if (b == e) return;
  bool act = lane < H * LPH;
  int idx = lane * 4;
  int head = lane / LPH;
  float4 q4 = make_float4(0.f, 0.f, 0.f, 0.f), We4 = q4;
  if (act) {
    u16x4 qv = *(const u16x4*)(q + (size_t)w * HC + idx);
    q4.x = bf2f(qv.x); q4.y = bf2f(qv.y); q4.z = bf2f(qv.z); q4.w = bf2f(qv.w);
    We4 = *(const float4*)(We + idx);
  }
  float m = -INFINITY, l = 0.f;
  float4 acc = make_float4(0.f, 0.f, 0.f, 0.f);

  auto step = [&](u16x4 kv, u16x4 vv, float eav, int pos) {
    float4 k4, v4;
    k4.x = fmaf(eav, We4.x, bf2f(kv.x));
    k4.y = fmaf(eav, We4.y, bf2f(kv.y));
    k4.z = fmaf(eav, We4.z, bf2f(kv.z));
    k4.w = fmaf(eav, We4.w, bf2f(kv.w));
    v4.x = fmaf(eav, We4.x, bf2f(vv.x));
    v4.y = fmaf(eav, We4.y, bf2f(vv.y));
    v4.z = fmaf(eav, We4.z, bf2f(vv.z));
    v4.w = fmaf(eav, We4.w, bf2f(vv.w));
    float p = q4.x * k4.x + q4.y * k4.y + q4.z * k4.z + q4.w * k4.w;
#pragma unroll
    for (int mm = 1; mm < LPH; mm <<= 1) p += __shfl_xor(p, mm, 64);
    float score = p * scale;
    if (act && (lane % LPH) == 0) sc[(size_t)pos * H + head] = score;
    float mn = fmaxf(m, score);
    float f = __expf(m - mn);
    float es = __expf(score - mn);
    l = l * f + es;
    m = mn;
    acc.x = fmaf(acc.x, f, es * v4.x);
    acc.y = fmaf(acc.y, f, es * v4.y);
    acc.z = fmaf(acc.z, f, es * v4.z);
    acc.w = fmaf(acc.w, f, es * v4.w);
  };

  // prefetch stages A (even) and B (odd)
  u16x4 z4 = {0, 0, 0, 0};
  u16x4 kA = z4, vA = z4, kB = z4, vB = z4;
  float eaA = 0.f, eaB = 0.f;
  {
    int sA = src_s[b]; eaA = ea_s[b];
    if (act) {
      kA = *(const u16x4*)(k + (size_t)sA * HC + idx);
      vA = *(const u16x4*)(v + (size_t)sA * HC + idx);
    }
  }
  if (b + 1 < e) {
    int sB = src_s[b + 1]; eaB = ea_s[b + 1];
    if (act) {
      kB = *(const u16x4*)(k + (size_t)sB * HC + idx);
      vB = *(const u16x4*)(v + (size_t)sB * HC + idx);
    }
  }

  for (int pos = b; pos < e; pos += 2) {
    {
      u16x4 kc = kA, vc = vA; float eac = eaA;
      int pn = pos + 2;
      if (pn < e) {
        int sA = src_s[pn]; eaA = ea_s[pn];
        if (act) {
          kA = *(const u16x4*)(k + (size_t)sA * HC + idx);
          vA = *(const u16x4*)(v + (size_t)sA * HC + idx);
        }
      }
      step(kc, vc, eac, pos);
    }
    if (pos + 1 < e) {
      u16x4 kc = kB, vc = vB; float eac = eaB;
      int pn = pos + 3;
      if (pn < e) {
        int sB = src_s[pn]; eaB = ea_s[pn];
        if (act) {
          kB = *(const u16x4*)(k + (size_t)sB * HC + idx);
          vB = *(const u16x4*)(v + (size_t)sB * HC + idx);
        }
      }
      step(kc, vc, eac, pos + 1);
    }
  }

  float invl = 1.0f / (l + 1e-16f);
  if (act) {
    float* orow = outp + (size_t)w * HC + idx;
    float4 o = *(float4*)orow;
    o.x += acc.x * invl; o.y += acc.y * invl;
    o.z += acc.z * invl; o.w += acc.w * invl;
    *(float4*)orow = o;
  }
  for (int pos = b; pos < e; pos++) {
    if (act && (lane % LPH) == 0) {
      float sv = sc[(size_t)pos * H + head];
      alpha[(size_t)eid_s[pos] * H + head] = __expf(sv - m) * invl;
    }
  }
}

// ---------------- misc dense kernels ----------------

// LayerNorm + ReLU fused with hi/lo bf16 split (feeds next layer's GEMM A)
__global__ __launch_bounds__(256) void ln_relu_split(
    const float* __restrict__ in, const float* __restrict__ g,
    const float* __restrict__ b, unsigned short* __restrict__ hi,
    unsigned short* __restrict__ lo, int N) {
  int w = (blockIdx.x * 256 + threadIdx.x) >> 6;
  int lane = threadIdx.x & 63;
  if (w >= N) return;
  float4 x = *(const float4*)(in + (size_t)w * 256 + lane * 4);
  float s = x.x + x.y + x.z + x.w;
  float s2 = x.x * x.x + x.y * x.y + x.z * x.z + x.w * x.w;
  for (int m = 1; m < 64; m <<= 1) { s += __shfl_xor(s, m, 64); s2 += __shfl_xor(s2, m, 64); }
  float mu = s * (1.0f / 256.0f);
  float var = s2 * (1.0f / 256.0f) - mu * mu;
  float inv = rsqrtf(var + 1e-5f);
  float4 gv = *(const float4*)(g + lane * 4);
  float4 bv = *(const float4*)(b + lane * 4);
  float4 y;
  y.x = fmaxf(fmaf((x.x - mu) * inv, gv.x, bv.x), 0.f);
  y.y = fmaxf(fmaf((x.y - mu) * inv, gv.y, bv.y), 0.f);
  y.z = fmaxf(fmaf((x.z - mu) * inv, gv.z, bv.z), 0.f);
  y.w = fmaxf(fmaf((x.w - mu) * inv, gv.w, bv.w), 0.f);
  u16x4 yh, yl;
  yh.x = f2bf(y.x); yl.x = f2bf(y.x - bf2f(yh.x));
  yh.y = f2bf(y.y); yl.y = f2bf(y.y - bf2f(yh.y));
  yh.z = f2bf(y.z); yl.z = f2bf(y.z - bf2f(yh.z));
  yh.w = f2bf(y.w); yl.w = f2bf(y.w - bf2f(yh.w));
  *(u16x4*)(hi + (size_t)w * 256 + lane * 4) = yh;
  *(u16x4*)(lo + (size_t)w * 256 + lane * 4) = yl;
}

__global__ __launch_bounds__(192) void resid_pool2(
    const float* __restrict__ x, const float* __restrict__ x3,
    const int* __restrict__ batch, float* __restrict__ pooled,
    float* __restrict__ cnt, int N, int R) {
  int col = threadIdx.x;  // 0..191
  int r0 = blockIdx.x * R;
  int r1 = min(r0 + R, N);
  if (r0 >= N) return;
  float acc = 0.f;
  int cur = batch[r0];
  int run = 0;
  for (int r = r0; r < r1; r++) {
    int b = batch[r];
    if (b != cur) {
      atomicAdd(&pooled[cur * 192 + col], acc);
      if (col == 0) atomicAdd(&cnt[cur], (float)run);
      acc = 0.f; run = 0; cur = b;
    }
    size_t i = (size_t)r * 192 + col;
    acc += x[i] + fmaxf(x3[i], 0.f);
    run++;
  }
  atomicAdd(&pooled[cur * 192 + col], acc);
  if (col == 0) atomicAdd(&cnt[cur], (float)run);
}

__global__ __launch_bounds__(64) void head_mlp(
    const float* __restrict__ pooled, const float* __restrict__ cnt,
    const float* __restrict__ fc1w, const float* __restrict__ fc1b,
    const float* __restrict__ fc2w, const float* __restrict__ fc2b,
    float* __restrict__ logits) {
  int b = blockIdx.x;
  int t = threadIdx.x;
  __shared__ float p[192];
  __shared__ float hbuf[32];
  float inv = 1.0f / fmaxf(cnt[b], 1.0f);
  for (int i = t; i < 192; i += 64) p[i] = pooled[b * 192 + i] * inv;
  __syncthreads();
  if (t < 32) {
    float acc = fc1b[t];
    for (int i = 0; i < 192; i++) acc = fmaf(p[i], fc1w[i * 32 + t], acc);
    hbuf[t] = fmaxf(acc, 0.f);
  }
  __syncthreads();
  if (t < 2) {
    float acc = fc2b[t];
    for (int j = 0; j < 32; j++) acc = fmaf(hbuf[j], fc2w[j * 2 + t], acc);
    logits[b * 2 + t] = acc;
  }
}

static inline int divup(int a, int b) { return (a + b - 1) / b; }

extern "C" void kernel_launch(void* const* d_in, const int* in_sizes, int n_in,
                              void* d_out, int out_size, void* d_ws, size_t ws_size,
                              hipStream_t stream) {
  const int N = 20000, E = 320000, B = 64;
  const float* x     = (const float*)d_in[0];
  const int*   ei    = (const int*)d_in[1];
  const float* eattr = (const float*)d_in[2];
  const int*   batch = (const int*)d_in[3];
  const int* srcp = ei;
  const int* dstp = ei + E;

  const float* Wq[3]; const float* bq[3]; const float* Wk[3]; const float* bk[3];
  const float* Wv[3]; const float* bv[3]; const float* We[3]; const float* Ws[3];
  const float* bs[3];
  for (int l = 0; l < 3; l++) {
    int base = 4 + l * 9;
    Wq[l] = (const float*)d_in[base + 0]; bq[l] = (const float*)d_in[base + 1];
    Wk[l] = (const float*)d_in[base + 2]; bk[l] = (const float*)d_in[base + 3];
    Wv[l] = (const float*)d_in[base + 4]; bv[l] = (const float*)d_in[base + 5];
    We[l] = (const float*)d_in[base + 6];
    Ws[l] = (const float*)d_in[base + 7]; bs[l] = (const float*)d_in[base + 8];
  }
  const float* g1  = (const float*)d_in[31]; const float* be1 = (const float*)d_in[32];
  const float* g2  = (const float*)d_in[33]; const float* be2 = (const float*)d_in[34];
  const float* fc1w = (const float*)d_in[35]; const float* fc1b = (const float*)d_in[36];
  const float* fc2w = (const float*)d_in[37]; const float* fc2b = (const float*)d_in[38];

  float* out = (float*)d_out;
  float* logits = out;
  float* a1 = out + 128;
  float* a2 = a1 + (size_t)E * 4;
  float* a3 = a2 + (size_t)E * 4;

  float* ws = (float*)d_ws;
  size_t o = 0;
  float* qb = ws + o; o += (size_t)N * 256;   // bf16 q (ushort)
  float* kb = ws + o; o += (size_t)N * 256;   // bf16 k
  float* vb = ws + o; o += (size_t)N * 256;   // bf16 v
  float* xa = ws + o; o += (size_t)N * 256;
  float* xb = ws + o; o += (size_t)N * 256;
  float* sc = ws + o; o += (size_t)E * 6;
  int*   cntb  = (int*)(ws + o); o += N;
  int*   startb= (int*)(ws + o); o += N + 1;
  int*   offb  = (int*)(ws + o); o += N + 1;
  int*   src_s = (int*)(ws + o); o += E;
  float* ea_s  = ws + o; o += E;
  int*   eid_s = (int*)(ws + o); o += E;
  float* pooled = ws + o; o += (size_t)B * 192;
  float* cnt    = ws + o; o += B;
  unsigned short* Ah = (unsigned short*)(ws + o); o += (size_t)N * 128;
  unsigned short* Al = (unsigned short*)(ws + o); o += (size_t)N * 128;
  unsigned short* Wh12 = (unsigned short*)(ws + o); o += (size_t)12 * 32768;
  unsigned short* Wl12 = (unsigned short*)(ws + o); o += (size_t)12 * 32768;

  unsigned short* qh = (unsigned short*)qb;
  unsigned short* kh = (unsigned short*)kb;
  unsigned short* vh = (unsigned short*)vb;

  dim3 blk(256);

  struct LayerCfg { int K, M; float scale; };
  LayerCfg cfg[3] = {
    {192, 256, 0.125f},
    {256, 256, 0.125f},
    {256, 192, 0.1767766952966369f},
  };
  // ---- all 12 weight conversions in one launch ----
  CvtWArgs cwa;
  for (int l = 0; l < 3; l++) {
    cwa.W[l * 4 + 0] = Wq[l]; cwa.W[l * 4 + 1] = Wk[l];
    cwa.W[l * 4 + 2] = Wv[l]; cwa.W[l * 4 + 3] = Ws[l];
    for (int zz = 0; zz < 4; zz++) {
      cwa.K[l * 4 + zz] = cfg[l].K; cwa.M[l * 4 + zz] = cfg[l].M;
    }
  }
  cvt_w_all<<<12 * 65536 / 256, blk, 0, stream>>>(cwa, Wh12, Wl12);

  // ---- counting sort of edges by dst ----
  fill_i32<<<divup(N, 256), blk, 0, stream>>>(cntb, 0, N);
  hist_dst<<<divup(E, 256), blk, 0, stream>>>(dstp, cntb, E);
  scan_hist<<<1, dim3(1024), 0, stream>>>(cntb, startb, offb, N);
  scatter_edges<<<divup(E, 256), blk, 0, stream>>>(srcp, dstp, eattr, offb,
                                                  src_s, ea_s, eid_s, E);

  float*       lay_out[3] = {xa, xb, xa};
  float*       alpha_out[3] = {a1, a2, a3};

  // layer 1 input conversion (layers 2/3 get Ah/Al from ln_relu_split)
  cvt_split<<<divup(N * 192, 256), blk, 0, stream>>>(x, Ah, Al, N * 192);

  for (int l = 0; l < 3; l++) {
    int M = cfg[l].M;
    GemmArgs ga;
    float* outs[4] = {(float*)qh, (float*)kh, (float*)vh, lay_out[l]};
    const float* biases[4] = {bq[l], bk[l], bv[l], bs[l]};
    for (int z = 0; z < 4; z++) {
      ga.Wh[z] = Wh12 + (size_t)(l * 4 + z) * 65536;
      ga.Wl[z] = Wl12 + (size_t)(l * 4 + z) * 65536;
      ga.bias[z] = biases[z];
      ga.out[z] = outs[z];
      ga.obf[z] = (z < 3) ? 1 : 0;
    }
    dim3 gg((M >> 6) * 4, divup(N, 128));
    if (l == 0)      gemm4_lds<192><<<gg, blk, 0, stream>>>(Ah, Al, ga, N, M);
    else             gemm4_lds<256><<<gg, blk, 0, stream>>>(Ah, Al, ga, N, M);

    dim3 gat(divup(N * 64, 256));
    if (l < 2) {
      attn_fused<4, 16><<<gat, blk, 0, stream>>>(qh, kh, vh, We[l], startb, src_s,
                                                 ea_s, eid_s, sc, lay_out[l],
                                                 alpha_out[l], N, cfg[l].scale);
    } else {
      attn_fused<6, 8><<<gat, blk, 0, stream>>>(qh, kh, vh, We[l], startb, src_s,
                                                ea_s, eid_s, sc, lay_out[l],
                                                alpha_out[l], N, cfg[l].scale);
    }
    if (l == 0) ln_relu_split<<<divup(N, 4), blk, 0, stream>>>(xa, g1, be1, Ah, Al, N);
    if (l == 1) ln_relu_split<<<divup(N, 4), blk, 0, stream>>>(xb, g2, be2, Ah, Al, N);
  }

  fill_i32<<<divup(B * 192 + B, 256), blk, 0, stream>>>((int*)pooled, 0, B * 192 + B);
  resid_pool2<<<divup(N, 128), dim3(192), 0, stream>>>(x, xa, batch, pooled, cnt, N, 128);
  head_mlp<<<B, dim3(64), 0, stream>>>(pooled, cnt, fc1w, fc1b, fc2w, fc2b, logits);
}